// Round 13
// baseline (250.571 us; speedup 1.0000x reference)
//
#include <hip/hip_runtime.h>
#include <hip/hip_bf16.h>
#include <stdint.h>

typedef __bf16 bf16x8 __attribute__((ext_vector_type(8)));
typedef float f32x4 __attribute__((ext_vector_type(4)));
typedef float f32x2 __attribute__((ext_vector_type(2)));
typedef uint32_t u32x4 __attribute__((ext_vector_type(4)));
typedef uint32_t u32x2 __attribute__((ext_vector_type(2)));

// LDS XOR swizzle (Guideline 4): spreads 8 rows across distinct 16B slots.
__device__ __forceinline__ uint32_t swz(uint32_t row, uint32_t col, uint32_t strideB) {
    return (row * strideB + col * 2u) ^ ((row & 7u) << 4);
}
__device__ __forceinline__ unsigned short f2bf_bits(float v) {
    __bf16 h = (__bf16)v; return __builtin_bit_cast(unsigned short, h);
}
__device__ __forceinline__ float bf2f(__bf16 h) { return (float)h; }

// ===================== FAST PATH =====================
// ws element offsets (ushort) for weight blobs
#define OFF_BU_E    0         // [320][128]  (W1u | Wg1u)^T
#define OFF_BI_E    40960     // [320][128]  (W1i | Wg1i)^T
#define OFF_W2T_E   81920     // [128][256]  W2^T
#define OFF_W3T_E   114688    // [64][128]   W3^T
#define PREP_TOT    122880
#define OFF_TBL_B   262144    // tables start (byte offset)

__global__ void prep_weights_fast(const float* __restrict__ W1, const float* __restrict__ Wg1,
                                  const float* __restrict__ W2, const float* __restrict__ W3,
                                  unsigned short* __restrict__ ws) {
    int idx = blockIdx.x * 256 + threadIdx.x;
    if (idx >= PREP_TOT) return;
    float v;
    if (idx < OFF_BI_E) {                       // Bu[n][k] = W1[k][n] or Wg1[k][n-256], k user rows
        int n = idx >> 7, k = idx & 127;
        v = (n < 256) ? W1[k * 256 + n] : Wg1[k * 64 + (n - 256)];
    } else if (idx < OFF_W2T_E) {               // Bi: item rows k+128
        int loc = idx - OFF_BI_E; int n = loc >> 7, k = loc & 127;
        v = (n < 256) ? W1[(128 + k) * 256 + n] : Wg1[(128 + k) * 64 + (n - 256)];
    } else if (idx < OFF_W3T_E) {               // W2T [128n][256k]
        int loc = idx - OFF_W2T_E; int n = loc >> 8, k = loc & 255;
        v = W2[k * 128 + n];
    } else {                                    // W3T [64n][128k]
        int loc = idx - OFF_W3T_E; int n = loc >> 7, k = loc & 127;
        v = W3[k * 64 + n];
    }
    ws[idx] = f2bf_bits(v);
}

// Merged dense projection (user blocks then item blocks):
// [P | Pg](+bias for user) = H @ Bmat^T; also emits bf16 copy of H.
// P stored as fp8 e4m3 (MLP trunk tolerates ~6% rel err; dot/gate paths stay bf16).
// Round-13: 16-row / 256-thread blocks. Round-12's 32-row version still sat at
// ~2 blocks/CU (40 AGPR acc + staging ~110 regs/wave). 16 rows -> acc[5]=20
// AGPR, LDS 10.5KB -> 3-4 blocks/CU. This is a pure streaming kernel with a
// 230MB/6.3TB/s ~= 37us floor; residency is the only lever left.
#define POUT_STRIDE 328
__global__ __launch_bounds__(256, 2)
void proj_kernel(const float* __restrict__ HU, const float* __restrict__ HI,
                 const unsigned short* __restrict__ wsmat,
                 const float* __restrict__ b1, const float* __restrict__ bg1,
                 uint8_t* __restrict__ PU8, uint8_t* __restrict__ PI8,
                 unsigned short* __restrict__ PGU, unsigned short* __restrict__ PGI,
                 unsigned short* __restrict__ HU16, unsigned short* __restrict__ HI16,
                 int nu, int ni, int nbu) {
    // aliased: phase A = bf16 input tile [16][128] swz256 (4KB); phase B = out [16][328] (10.5KB)
    __shared__ __align__(16) unsigned short lds[16 * POUT_STRIDE];
    const int t = threadIdx.x, w = t >> 6, l = t & 63, l15 = l & 15, l4 = l >> 4;
    const bool isU = (int)blockIdx.x < nbu;
    const int rb = (isU ? (int)blockIdx.x : (int)blockIdx.x - nbu) * 16;
    const int rows = isU ? nu : ni;
    const float* H = isU ? HU : HI;
    const unsigned short* Bmat = wsmat + (isU ? OFF_BU_E : OFF_BI_E);
    uint8_t* P8 = isU ? PU8 : PI8;
    unsigned short* Pg  = isU ? PGU : PGI;
    unsigned short* H16 = isU ? HU16 : HI16;
    const int addBias = isU ? 1 : 0;

    {
        const int r = t >> 4, q = t & 15;   // 16 threads/row, 8 floats each
        int rg = rb + r; int rc = rg < rows ? rg : rows - 1;
        const float* p = H + (size_t)rc * 128 + q * 8;
        f32x4 f0 = *(const f32x4*)(p);
        f32x4 f1 = *(const f32x4*)(p + 4);
        bf16x8 h0;
        #pragma unroll
        for (int j = 0; j < 4; ++j) { h0[j] = (__bf16)f0[j]; h0[j + 4] = (__bf16)f1[j]; }
        *(bf16x8*)((char*)lds + swz(r, q * 8, 256)) = h0;
        if (rg < rows) *(bf16x8*)(H16 + (size_t)rg * 128 + q * 8) = h0;
    }
    __syncthreads();
    // GEMM: M=16, K=128, N=320. Wave w -> cols w*80..+79 (5 n-tiles)
    f32x4 acc[5] = {};
    #pragma unroll
    for (int kt = 0; kt < 4; ++kt) {
        bf16x8 aA = *(const bf16x8*)((const char*)lds + swz(l15, kt * 32 + l4 * 8, 256));
        #pragma unroll
        for (int nt = 0; nt < 5; ++nt) {
            const int n = w * 80 + nt * 16 + l15;
            bf16x8 bfr = *(const bf16x8*)(Bmat + n * 128 + kt * 32 + l4 * 8);
            acc[nt] = __builtin_amdgcn_mfma_f32_16x16x32_bf16(aA, bfr, acc[nt], 0, 0, 0);
        }
    }
    __syncthreads();   // input-tile reads done; reuse lds as output stage
    #pragma unroll
    for (int nt = 0; nt < 5; ++nt) {
        const int n = w * 80 + nt * 16 + l15;
        const float bias = addBias ? ((n < 256) ? b1[n] : bg1[n - 256]) : 0.f;
        #pragma unroll
        for (int j = 0; j < 4; ++j) {
            const int row = l4 * 4 + j;
            lds[row * POUT_STRIDE + n] = f2bf_bits(acc[nt][j] + bias);  // NO relu here
        }
    }
    __syncthreads();
    {
        const int r = t >> 4, q = t & 15;   // 16 threads/row; 16 P-cols + 4 Pg-cols each
        const int rg = rb + r;
        if (rg < rows) {
            uint32_t dw[4];
            #pragma unroll
            for (int vb = 0; vb < 2; ++vb) {
                bf16x8 pv = *(const bf16x8*)(&lds[r * POUT_STRIDE + q * 16 + vb * 8]);
                float f[8];
                #pragma unroll
                for (int j = 0; j < 8; ++j) f[j] = bf2f(pv[j]);
                uint32_t d0 = 0, d1 = 0;
                d0 = __builtin_amdgcn_cvt_pk_fp8_f32(f[0], f[1], d0, false);
                d0 = __builtin_amdgcn_cvt_pk_fp8_f32(f[2], f[3], d0, true);
                d1 = __builtin_amdgcn_cvt_pk_fp8_f32(f[4], f[5], d1, false);
                d1 = __builtin_amdgcn_cvt_pk_fp8_f32(f[6], f[7], d1, true);
                dw[vb * 2] = d0; dw[vb * 2 + 1] = d1;
            }
            u32x4 s0 = {dw[0], dw[1], dw[2], dw[3]};
            *(u32x4*)(P8 + (size_t)rg * 256 + q * 16) = s0;
            u32x2 gv = *(const u32x2*)(&lds[r * POUT_STRIDE + 256 + q * 4]);
            *(u32x2*)(Pg + (size_t)rg * 64 + q * 4) = gv;
        }
    }
}

#define GRID_MAIN 2048   // 256-thr persistent blocks

// Persistent main kernel, 256 threads / 4 waves, ETILE=32 — round-11/12 (best: 146us).
// 3 barriers/iter; parity double-buffer removes sync4 (the only barrier whose
// vmcnt drain waited on the out[] store). Round-9 lesson: no asm barriers.
// Round-10 lesson: keep phase3 spread over all 4 waves.
__global__ __launch_bounds__(256, 2)
void edge_main(const int* __restrict__ src, const int* __restrict__ dst,
               const uint8_t* __restrict__ PU8, const uint8_t* __restrict__ PI8,
               const unsigned short* __restrict__ PGU, const unsigned short* __restrict__ PGI,
               const unsigned short* __restrict__ HU16, const unsigned short* __restrict__ HI16,
               const unsigned short* __restrict__ W2T, const unsigned short* __restrict__ W3T,
               const float* __restrict__ b2, const float* __restrict__ b3,
               const float* __restrict__ b4, const float* __restrict__ W4,
               const float* __restrict__ Wg2, const float* __restrict__ bg2,
               float* __restrict__ out, int E) {
    __shared__ __align__(16) unsigned short lds_x1[32 * 256];  // 16KB, swz 512
    __shared__ __align__(16) unsigned short lds_x2[32 * 128];  // 8KB, swz 256
    __shared__ float lds_dot[2][32], lds_g0[2][32], lds_g1[2][32];  // parity dbuf
    __shared__ float lds_mlp[2][4][32];
    __shared__ float lds_wg0[64], lds_wg1[64];                 // Wg2 columns (512B)

    const int t = threadIdx.x, w = t >> 6, l = t & 63, l15 = l & 15, l4 = l >> 4;
    const int r = t >> 3, q = t & 7;        // gather roles: edge slot r (0..31), chunk q

    // per-wave column bases: x2 -> cols w*32..+31 ; x3 -> cols w*16..+15
    const unsigned short* w2p = W2T + (w * 32 + l15) * 256 + l4 * 8;   // nt=1 adds 16*256
    const unsigned short* w3p = W3T + (w * 16 + l15) * 128 + l4 * 8;
    float b2v[2];
    #pragma unroll
    for (int nt = 0; nt < 2; ++nt) b2v[nt] = b2[w * 32 + nt * 16 + l15];
    const float b3v = b3[w * 16 + l15], w4v = W4[w * 16 + l15];
    const float bg2_0 = bg2[0], bg2_1 = bg2[1], b4_0 = b4[0];

    if (t < 64) { lds_wg0[t] = Wg2[t * 2]; lds_wg1[t] = Wg2[t * 2 + 1]; }

    const int NT = (E + 31) >> 5;
    int tile = blockIdx.x;
    if (tile >= NT) return;

    u32x4 gpu8[2], gpi8[2];
    bf16x8 ghu[2], ghi[2], gpg_u, gpg_i;
#define ISSUE(TT) do { \
        int e_ = (TT) * 32 + r; if (e_ >= E) e_ = E - 1; \
        const int sA_ = src[e_], dA_ = dst[e_]; \
        const uint8_t* pu_ = PU8 + (size_t)sA_ * 256 + q * 32; \
        const uint8_t* pi_ = PI8 + (size_t)dA_ * 256 + q * 32; \
        const unsigned short* hu_ = HU16 + (size_t)sA_ * 128 + q * 16; \
        const unsigned short* hi_ = HI16 + (size_t)dA_ * 128 + q * 16; \
        gpu8[0] = *(const u32x4*)(pu_);      gpu8[1] = *(const u32x4*)(pu_ + 16); \
        gpi8[0] = *(const u32x4*)(pi_);      gpi8[1] = *(const u32x4*)(pi_ + 16); \
        ghu[0] = *(const bf16x8*)(hu_);      ghu[1] = *(const bf16x8*)(hu_ + 8); \
        ghi[0] = *(const bf16x8*)(hi_);      ghi[1] = *(const bf16x8*)(hi_ + 8); \
        gpg_u = *(const bf16x8*)(PGU + (size_t)sA_ * 64 + q * 8); \
        gpg_i = *(const bf16x8*)(PGI + (size_t)dA_ * 64 + q * 8); \
    } while (0)

    ISSUE(tile);
    __syncthreads();   // prologue: lds_wg ready

    int pb = 0;
    for (;;) {
        // ---- phase 1: x1 = relu(fp8(P_u)+fp8(P_i)) -> LDS bf16; dot; gates -> [pb]
        #pragma unroll
        for (int v = 0; v < 2; ++v) {
            #pragma unroll
            for (int h = 0; h < 2; ++h) {
                bf16x8 o;
                #pragma unroll
                for (int d = 0; d < 2; ++d) {
                    const uint32_t du = gpu8[v][2 * h + d], di = gpi8[v][2 * h + d];
                    f32x2 a0 = __builtin_amdgcn_cvt_pk_f32_fp8(du, false);
                    f32x2 a1 = __builtin_amdgcn_cvt_pk_f32_fp8(du, true);
                    f32x2 c0 = __builtin_amdgcn_cvt_pk_f32_fp8(di, false);
                    f32x2 c1 = __builtin_amdgcn_cvt_pk_f32_fp8(di, true);
                    o[d * 4 + 0] = (__bf16)fmaxf(a0[0] + c0[0], 0.f);
                    o[d * 4 + 1] = (__bf16)fmaxf(a0[1] + c0[1], 0.f);
                    o[d * 4 + 2] = (__bf16)fmaxf(a1[0] + c1[0], 0.f);
                    o[d * 4 + 3] = (__bf16)fmaxf(a1[1] + c1[1], 0.f);
                }
                *(bf16x8*)((char*)lds_x1 + swz(r, q * 32 + v * 16 + h * 8, 512)) = o;
            }
        }
        {
            float dacc = 0.f;
            #pragma unroll
            for (int v = 0; v < 2; ++v)
                #pragma unroll
                for (int j = 0; j < 8; ++j)
                    dacc += bf2f(ghu[v][j]) * bf2f(ghi[v][j]);
            dacc += __shfl_xor(dacc, 1); dacc += __shfl_xor(dacc, 2); dacc += __shfl_xor(dacc, 4);
            f32x4 wg0a = *(const f32x4*)(&lds_wg0[q * 8]);
            f32x4 wg0b = *(const f32x4*)(&lds_wg0[q * 8 + 4]);
            f32x4 wg1a = *(const f32x4*)(&lds_wg1[q * 8]);
            f32x4 wg1b = *(const f32x4*)(&lds_wg1[q * 8 + 4]);
            float g0 = 0.f, g1 = 0.f;
            #pragma unroll
            for (int i = 0; i < 4; ++i) {
                float va = fmaxf(bf2f(gpg_u[i]) + bf2f(gpg_i[i]), 0.f);
                float vb = fmaxf(bf2f(gpg_u[i + 4]) + bf2f(gpg_i[i + 4]), 0.f);
                g0 += va * wg0a[i] + vb * wg0b[i];
                g1 += va * wg1a[i] + vb * wg1b[i];
            }
            g0 += __shfl_xor(g0, 1); g0 += __shfl_xor(g0, 2); g0 += __shfl_xor(g0, 4);
            g1 += __shfl_xor(g1, 1); g1 += __shfl_xor(g1, 2); g1 += __shfl_xor(g1, 4);
            if (q == 0) { lds_dot[pb][r] = dacc; lds_g0[pb][r] = g0; lds_g1[pb][r] = g1; }
        }
        __syncthreads();   // sync1: x1/dot/gates visible

        const int ntile = tile + GRID_MAIN;
        const bool hn = ntile < NT;
        if (hn) ISSUE(ntile);   // T14 prefetch; drains at sync2 (cover = phase 2)

        // ---- phase 2: x2 = relu(x1 @ W2 + b2): 32 rows, wave w -> cols w*32..+31
        {
            f32x4 acc2[2][2] = {};
            #pragma unroll
            for (int kt = 0; kt < 8; ++kt) {
                bf16x8 aA = *(const bf16x8*)((const char*)lds_x1 + swz(l15, kt * 32 + l4 * 8, 512));
                bf16x8 aB = *(const bf16x8*)((const char*)lds_x1 + swz(16 + l15, kt * 32 + l4 * 8, 512));
                bf16x8 bf0 = *(const bf16x8*)(w2p + kt * 32);
                bf16x8 bf1 = *(const bf16x8*)(w2p + 16 * 256 + kt * 32);
                acc2[0][0] = __builtin_amdgcn_mfma_f32_16x16x32_bf16(aA, bf0, acc2[0][0], 0, 0, 0);
                acc2[1][0] = __builtin_amdgcn_mfma_f32_16x16x32_bf16(aB, bf0, acc2[1][0], 0, 0, 0);
                acc2[0][1] = __builtin_amdgcn_mfma_f32_16x16x32_bf16(aA, bf1, acc2[0][1], 0, 0, 0);
                acc2[1][1] = __builtin_amdgcn_mfma_f32_16x16x32_bf16(aB, bf1, acc2[1][1], 0, 0, 0);
            }
            #pragma unroll
            for (int mt = 0; mt < 2; ++mt)
                #pragma unroll
                for (int nt = 0; nt < 2; ++nt) {
                    const int col = w * 32 + nt * 16 + l15;
                    #pragma unroll
                    for (int j = 0; j < 4; ++j) {
                        const int row = mt * 16 + l4 * 4 + j;
                        float v = fmaxf(acc2[mt][nt][j] + b2v[nt], 0.f);
                        *(unsigned short*)((char*)lds_x2 + swz(row, col, 256)) = f2bf_bits(v);
                    }
                }
        }
        __syncthreads();   // sync2: x2 ready; x1 free

        // ---- phase 3: x3 = relu(x2 @ W3 + b3), fused W4 head: wave w -> cols w*16..+15
        {
            f32x4 acc3[2] = {};
            #pragma unroll
            for (int kt = 0; kt < 4; ++kt) {
                bf16x8 a0 = *(const bf16x8*)((const char*)lds_x2 + swz(l15, kt * 32 + l4 * 8, 256));
                bf16x8 a1 = *(const bf16x8*)((const char*)lds_x2 + swz(16 + l15, kt * 32 + l4 * 8, 256));
                bf16x8 bfr = *(const bf16x8*)(w3p + kt * 32);
                acc3[0] = __builtin_amdgcn_mfma_f32_16x16x32_bf16(a0, bfr, acc3[0], 0, 0, 0);
                acc3[1] = __builtin_amdgcn_mfma_f32_16x16x32_bf16(a1, bfr, acc3[1], 0, 0, 0);
            }
            float mp[2][4];
            #pragma unroll
            for (int mt = 0; mt < 2; ++mt)
                #pragma unroll
                for (int j = 0; j < 4; ++j) {
                    mp[mt][j] = fmaxf(acc3[mt][j] + b3v, 0.f) * w4v;
                    mp[mt][j] += __shfl_xor(mp[mt][j], 1);
                    mp[mt][j] += __shfl_xor(mp[mt][j], 2);
                    mp[mt][j] += __shfl_xor(mp[mt][j], 4);
                    mp[mt][j] += __shfl_xor(mp[mt][j], 8);
                }
            if (l15 == 0) {
                #pragma unroll
                for (int mt = 0; mt < 2; ++mt)
                    #pragma unroll
                    for (int j = 0; j < 4; ++j)
                        lds_mlp[pb][w][mt * 16 + l4 * 4 + j] = mp[mt][j];
            }
        }
        __syncthreads();   // sync3: mlp partials ready

        if (t < 32) {
            const int e = tile * 32 + t;
            if (e < E) {
                const float mlp = lds_mlp[pb][0][t] + lds_mlp[pb][1][t] + lds_mlp[pb][2][t]
                                + lds_mlp[pb][3][t] + b4_0;
                const float dot = lds_dot[pb][t];
                const float L0 = lds_g0[pb][t] + bg2_0, L1 = lds_g1[pb][t] + bg2_1;
                const float d = L1 - L0;
                const float z = __expf(-fabsf(d));
                const float inv = 1.f / (1.f + z);
                const float g1s = (d >= 0.f) ? inv : z * inv;
                out[e] = (1.f - g1s) * dot + g1s * mlp;
            }
        }
        // no sync4: parity buffers make the next iteration's writes hazard-free
        if (!hn) break;
        tile = ntile;
        pb ^= 1;
    }
#undef ISSUE
}

// ===================== FALLBACK (used only if ws too small) =====================
#define FB_ETILE 128
#define FB_WT1_OFF 0
#define FB_WT2_OFF 65536
#define FB_WT3_OFF 98304
#define FB_WTG1_OFF 106496
#define FB_WTOT 122880

__global__ void prep_weights_fb(const float* __restrict__ W1, const float* __restrict__ W2,
                                const float* __restrict__ W3, const float* __restrict__ Wg1,
                                unsigned short* __restrict__ ws) {
    int idx = blockIdx.x * 256 + threadIdx.x;
    if (idx >= FB_WTOT) return;
    float v;
    if (idx < FB_WT2_OFF)      { int n = idx >> 8, k = idx & 255; v = W1[k * 256 + n]; }
    else if (idx < FB_WT3_OFF) { int loc = idx - FB_WT2_OFF; int n = loc >> 8, k = loc & 255; v = W2[k * 128 + n]; }
    else if (idx < FB_WTG1_OFF){ int loc = idx - FB_WT3_OFF; int n = loc >> 7, k = loc & 127; v = W3[k * 64 + n]; }
    else                       { int loc = idx - FB_WTG1_OFF; int n = loc >> 8, k = loc & 255; v = Wg1[k * 64 + n]; }
    ws[idx] = f2bf_bits(v);
}

__global__ __launch_bounds__(512, 2)
void fused_edge_kernel_fb(const float* __restrict__ h_user, const float* __restrict__ h_item,
                          const int* __restrict__ src, const int* __restrict__ dst,
                          const unsigned short* __restrict__ wsmat,
                          const float* __restrict__ b1, const float* __restrict__ b2,
                          const float* __restrict__ b3, const float* __restrict__ b4,
                          const float* __restrict__ W4, const float* __restrict__ bg1,
                          const float* __restrict__ Wg2, const float* __restrict__ bg2,
                          float* __restrict__ out, int E) {
    __shared__ __align__(16) unsigned short lds_e[FB_ETILE * 256];
    __shared__ __align__(16) unsigned short lds_x1[FB_ETILE * 256];
    __shared__ float lds_dot[FB_ETILE];
    const unsigned short* wt1  = wsmat + FB_WT1_OFF;
    const unsigned short* wt2  = wsmat + FB_WT2_OFF;
    const unsigned short* wt3  = wsmat + FB_WT3_OFF;
    const unsigned short* wtg1 = wsmat + FB_WTG1_OFF;
    const int t = threadIdx.x, eb = blockIdx.x * FB_ETILE;
    const int w = t >> 6, l = t & 63, l15 = l & 15, l4 = l >> 4;
    {
        const int r = t >> 2, q = t & 3;
        int e = eb + r; if (e >= E) e = E - 1;
        const int idx = (q < 2) ? src[e] : dst[e];
        const float* rowp = ((q < 2) ? h_user : h_item) + (size_t)idx * 128 + (q & 1) * 64;
        const uint32_t cbase = (uint32_t)q * 64u;
        #pragma unroll
        for (int i = 0; i < 8; ++i) {
            f32x4 a = *reinterpret_cast<const f32x4*>(rowp + i * 8);
            f32x4 b = *reinterpret_cast<const f32x4*>(rowp + i * 8 + 4);
            bf16x8 p;
            #pragma unroll
            for (int j = 0; j < 4; ++j) { p[j] = (__bf16)a[j]; p[j + 4] = (__bf16)b[j]; }
            *reinterpret_cast<bf16x8*>((char*)lds_e + swz(r, cbase + i * 8u, 512)) = p;
        }
    }
    __syncthreads();
    {
        const int r = t >> 2, q = t & 3;
        float acc = 0.f;
        #pragma unroll
        for (int i = 0; i < 4; ++i) {
            uint32_t c = (uint32_t)q * 32u + i * 8u;
            bf16x8 sv = *reinterpret_cast<const bf16x8*>((const char*)lds_e + swz(r, c, 512));
            bf16x8 dv = *reinterpret_cast<const bf16x8*>((const char*)lds_e + swz(r, 128u + c, 512));
            #pragma unroll
            for (int j = 0; j < 8; ++j) acc += (float)sv[j] * (float)dv[j];
        }
        acc += __shfl_xor(acc, 1); acc += __shfl_xor(acc, 2);
        if (q == 0) lds_dot[r] = acc;
    }
    {
        const int mg = w >> 2, cg = w & 3;
        f32x4 acc[4][4] = {};
        #pragma unroll
        for (int kh = 0; kh < 2; ++kh) {
            bf16x8 afr[4][4];
            #pragma unroll
            for (int mt = 0; mt < 4; ++mt)
                #pragma unroll
                for (int kt = 0; kt < 4; ++kt)
                    afr[mt][kt] = *reinterpret_cast<const bf16x8*>((const char*)lds_e +
                        swz(mg * 64 + mt * 16 + l15, kh * 128 + kt * 32 + l4 * 8, 512));
            #pragma unroll
            for (int nt = 0; nt < 4; ++nt) {
                const int n = cg * 64 + nt * 16 + l15;
                #pragma unroll
                for (int kt = 0; kt < 4; ++kt) {
                    bf16x8 bfr = *reinterpret_cast<const bf16x8*>(wt1 + n * 256 + kh * 128 + kt * 32 + l4 * 8);
                    #pragma unroll
                    for (int mt = 0; mt < 4; ++mt)
                        acc[mt][nt] = __builtin_amdgcn_mfma_f32_16x16x32_bf16(afr[mt][kt], bfr, acc[mt][nt], 0, 0, 0);
                }
            }
        }
        #pragma unroll
        for (int nt = 0; nt < 4; ++nt) {
            const int col = cg * 64 + nt * 16 + l15;
            const float bias = b1[col];
            #pragma unroll
            for (int mt = 0; mt < 4; ++mt) {
                const int row0 = mg * 64 + mt * 16 + l4 * 4;
                #pragma unroll
                for (int j = 0; j < 4; ++j) {
                    float v = fmaxf(acc[mt][nt][j] + bias, 0.f);
                    *reinterpret_cast<unsigned short*>((char*)lds_x1 + swz(row0 + j, col, 512)) = f2bf_bits(v);
                }
            }
        }
    }
    float l0p[4] = {0, 0, 0, 0}, l1p[4] = {0, 0, 0, 0};
    {
        bf16x8 ag[8];
        #pragma unroll
        for (int kt = 0; kt < 8; ++kt)
            ag[kt] = *reinterpret_cast<const bf16x8*>((const char*)lds_e + swz(w * 16 + l15, kt * 32 + l4 * 8, 512));
        f32x4 accg[4] = {};
        #pragma unroll
        for (int nt = 0; nt < 4; ++nt) {
            const int n = nt * 16 + l15;
            #pragma unroll
            for (int kt = 0; kt < 8; ++kt) {
                bf16x8 bfr = *reinterpret_cast<const bf16x8*>(wtg1 + n * 256 + kt * 32 + l4 * 8);
                accg[nt] = __builtin_amdgcn_mfma_f32_16x16x32_bf16(ag[kt], bfr, accg[nt], 0, 0, 0);
            }
        }
        #pragma unroll
        for (int nt = 0; nt < 4; ++nt) {
            const int col = nt * 16 + l15;
            const float bg = bg1[col];
            const float w0 = Wg2[col * 2 + 0], w1 = Wg2[col * 2 + 1];
            #pragma unroll
            for (int j = 0; j < 4; ++j) {
                float v = fmaxf(accg[nt][j] + bg, 0.f);
                l0p[j] += v * w0; l1p[j] += v * w1;
            }
        }
        #pragma unroll
        for (int j = 0; j < 4; ++j)
            #pragma unroll
            for (int m = 1; m < 16; m <<= 1) {
                l0p[j] += __shfl_xor(l0p[j], m);
                l1p[j] += __shfl_xor(l1p[j], m);
            }
    }
    __syncthreads();
    {
        const int mg = w >> 1, cg = w & 1;
        bf16x8 a2[2][8];
        #pragma unroll
        for (int mt = 0; mt < 2; ++mt)
            #pragma unroll
            for (int kt = 0; kt < 8; ++kt)
                a2[mt][kt] = *reinterpret_cast<const bf16x8*>((const char*)lds_x1 +
                    swz(mg * 32 + mt * 16 + l15, kt * 32 + l4 * 8, 512));
        f32x4 acc2[2][4] = {};
        #pragma unroll
        for (int nt = 0; nt < 4; ++nt) {
            const int n = cg * 64 + nt * 16 + l15;
            #pragma unroll
            for (int kt = 0; kt < 8; ++kt) {
                bf16x8 bfr = *reinterpret_cast<const bf16x8*>(wt2 + n * 256 + kt * 32 + l4 * 8);
                #pragma unroll
                for (int mt = 0; mt < 2; ++mt)
                    acc2[mt][nt] = __builtin_amdgcn_mfma_f32_16x16x32_bf16(a2[mt][kt], bfr, acc2[mt][nt], 0, 0, 0);
            }
        }
        #pragma unroll
        for (int nt = 0; nt < 4; ++nt) {
            const int col = cg * 64 + nt * 16 + l15;
            const float bias = b2[col];
            #pragma unroll
            for (int mt = 0; mt < 2; ++mt) {
                const int row0 = mg * 32 + mt * 16 + l4 * 4;
                #pragma unroll
                for (int j = 0; j < 4; ++j) {
                    float v = fmaxf(acc2[mt][nt][j] + bias, 0.f);
                    *reinterpret_cast<unsigned short*>((char*)lds_e + swz(row0 + j, col, 256)) = f2bf_bits(v);
                }
            }
        }
    }
    __syncthreads();
    {
        float mlpp[4] = {0, 0, 0, 0};
        bf16x8 a3[4];
        #pragma unroll
        for (int kt = 0; kt < 4; ++kt)
            a3[kt] = *reinterpret_cast<const bf16x8*>((const char*)lds_e + swz(w * 16 + l15, kt * 32 + l4 * 8, 256));
        f32x4 acc3[4] = {};
        #pragma unroll
        for (int nt = 0; nt < 4; ++nt) {
            const int n = nt * 16 + l15;
            #pragma unroll
            for (int kt = 0; kt < 4; ++kt) {
                bf16x8 bfr = *reinterpret_cast<const bf16x8*>(wt3 + n * 128 + kt * 32 + l4 * 8);
                acc3[nt] = __builtin_amdgcn_mfma_f32_16x16x32_bf16(a3[kt], bfr, acc3[nt], 0, 0, 0);
            }
        }
        #pragma unroll
        for (int nt = 0; nt < 4; ++nt) {
            const int col = nt * 16 + l15;
            const float b3v = b3[col];
            const float w4v = W4[col];
            #pragma unroll
            for (int j = 0; j < 4; ++j) {
                float v = fmaxf(acc3[nt][j] + b3v, 0.f);
                mlpp[j] += v * w4v;
            }
        }
        #pragma unroll
        for (int j = 0; j < 4; ++j)
            #pragma unroll
            for (int m = 1; m < 16; m <<= 1)
                mlpp[j] += __shfl_xor(mlpp[j], m);
        if (l15 == 0) {
            #pragma unroll
            for (int j = 0; j < 4; ++j) {
                const int rr = w * 16 + l4 * 4 + j;
                const int e = eb + rr;
                if (e < E) {
                    const float dot = lds_dot[rr];
                    const float mlp = mlpp[j] + b4[0];
                    const float L0 = l0p[j] + bg2[0];
                    const float L1 = l1p[j] + bg2[1];
                    const float d = L1 - L0;
                    const float z = __expf(-fabsf(d));
                    const float inv = 1.f / (1.f + z);
                    const float g1 = (d >= 0.f) ? inv : z * inv;
                    out[e] = (1.f - g1) * dot + g1 * mlp;
                }
            }
        }
    }
}

// ===================== launch =====================
extern "C" void kernel_launch(void* const* d_in, const int* in_sizes, int n_in,
                              void* d_out, int out_size, void* d_ws, size_t ws_size,
                              hipStream_t stream) {
    const float* h_user = (const float*)d_in[0];
    const float* h_item = (const float*)d_in[1];
    const int*   src    = (const int*)d_in[2];
    const int*   dst    = (const int*)d_in[3];
    const float* W1  = (const float*)d_in[4];
    const float* b1  = (const float*)d_in[5];
    const float* W2  = (const float*)d_in[6];
    const float* b2  = (const float*)d_in[7];
    const float* W3  = (const float*)d_in[8];
    const float* b3  = (const float*)d_in[9];
    const float* W4  = (const float*)d_in[10];
    const float* b4  = (const float*)d_in[11];
    const float* Wg1 = (const float*)d_in[12];
    const float* bg1 = (const float*)d_in[13];
    const float* Wg2 = (const float*)d_in[14];
    const float* bg2 = (const float*)d_in[15];
    const int E  = in_sizes[2];
    const int nu = in_sizes[0] / 128;
    const int ni = in_sizes[1] / 128;

    unsigned short* ws = (unsigned short*)d_ws;
    char* wsb = (char*)d_ws;

    // fast-path table layout (byte offsets past the bf16 weight blob)
    size_t off = OFF_TBL_B;
    uint8_t* PU8 = (uint8_t*)(wsb + off); off += (size_t)nu * 256;
    uint8_t* PI8 = (uint8_t*)(wsb + off); off += (size_t)ni * 256;
    unsigned short* PGU  = (unsigned short*)(wsb + off); off += (size_t)nu * 128;
    unsigned short* PGI  = (unsigned short*)(wsb + off); off += (size_t)ni * 128;
    unsigned short* HU16 = (unsigned short*)(wsb + off); off += (size_t)nu * 256;
    unsigned short* HI16 = (unsigned short*)(wsb + off); off += (size_t)ni * 256;
    const size_t need_bytes = off;

    if (ws_size >= need_bytes) {
        prep_weights_fast<<<(PREP_TOT + 255) / 256, 256, 0, stream>>>(W1, Wg1, W2, W3, ws);
        const int nbu = (nu + 15) / 16, nbi = (ni + 15) / 16;
        proj_kernel<<<nbu + nbi, 256, 0, stream>>>(h_user, h_item, ws, b1, bg1,
                                                   PU8, PI8, PGU, PGI, HU16, HI16, nu, ni, nbu);
        edge_main<<<GRID_MAIN, 256, 0, stream>>>(src, dst, PU8, PI8, PGU, PGI, HU16, HI16,
                                                 ws + OFF_W2T_E, ws + OFF_W3T_E,
                                                 b2, b3, b4, W4, Wg2, bg2, (float*)d_out, E);
    } else {
        prep_weights_fb<<<(FB_WTOT + 255) / 256, 256, 0, stream>>>(W1, W2, W3, Wg1, ws);
        const int nblk = (E + FB_ETILE - 1) / FB_ETILE;
        fused_edge_kernel_fb<<<nblk, 512, 0, stream>>>(h_user, h_item, src, dst, ws,
                                                       b1, b2, b3, b4, W4, bg1, Wg2, bg2,
                                                       (float*)d_out, E);
    }
}

// Round 14
// 209.300 us; speedup vs baseline: 1.1972x; 1.1972x over previous
//
#include <hip/hip_runtime.h>
#include <hip/hip_bf16.h>
#include <stdint.h>

typedef __bf16 bf16x8 __attribute__((ext_vector_type(8)));
typedef float f32x4 __attribute__((ext_vector_type(4)));
typedef float f32x2 __attribute__((ext_vector_type(2)));
typedef uint32_t u32x4 __attribute__((ext_vector_type(4)));

// LDS XOR swizzle (Guideline 4): spreads 8 rows across distinct 16B slots.
__device__ __forceinline__ uint32_t swz(uint32_t row, uint32_t col, uint32_t strideB) {
    return (row * strideB + col * 2u) ^ ((row & 7u) << 4);
}
__device__ __forceinline__ unsigned short f2bf_bits(float v) {
    __bf16 h = (__bf16)v; return __builtin_bit_cast(unsigned short, h);
}
__device__ __forceinline__ float bf2f(__bf16 h) { return (float)h; }

// ===================== FAST PATH =====================
// ws element offsets (ushort) for weight blobs
#define OFF_BU_E    0         // [320][128]  (W1u | Wg1u)^T
#define OFF_BI_E    40960     // [320][128]  (W1i | Wg1i)^T
#define OFF_W2T_E   81920     // [128][256]  W2^T
#define OFF_W3T_E   114688    // [64][128]   W3^T
#define PREP_TOT    122880
#define OFF_TBL_B   262144    // tables start (byte offset)

__global__ void prep_weights_fast(const float* __restrict__ W1, const float* __restrict__ Wg1,
                                  const float* __restrict__ W2, const float* __restrict__ W3,
                                  unsigned short* __restrict__ ws) {
    int idx = blockIdx.x * 256 + threadIdx.x;
    if (idx >= PREP_TOT) return;
    float v;
    if (idx < OFF_BI_E) {                       // Bu[n][k] = W1[k][n] or Wg1[k][n-256], k user rows
        int n = idx >> 7, k = idx & 127;
        v = (n < 256) ? W1[k * 256 + n] : Wg1[k * 64 + (n - 256)];
    } else if (idx < OFF_W2T_E) {               // Bi: item rows k+128
        int loc = idx - OFF_BI_E; int n = loc >> 7, k = loc & 127;
        v = (n < 256) ? W1[(128 + k) * 256 + n] : Wg1[(128 + k) * 64 + (n - 256)];
    } else if (idx < OFF_W3T_E) {               // W2T [128n][256k]
        int loc = idx - OFF_W2T_E; int n = loc >> 8, k = loc & 255;
        v = W2[k * 128 + n];
    } else {                                    // W3T [64n][128k]
        int loc = idx - OFF_W3T_E; int n = loc >> 7, k = loc & 127;
        v = W3[k * 64 + n];
    }
    ws[idx] = f2bf_bits(v);
}

// Merged dense projection (user blocks then item blocks):
// [P | Pg](+bias for user) = H @ Bmat^T; also emits bf16 copy of H.
// P stored as fp8 e4m3 (MLP trunk tolerates ~6% rel err; dot/gate paths stay bf16).
// 32-row / 256-thread blocks = measured optimum (round-12: ~56us).
// Round-13 lesson: 16-row blocks regressed 56->146us — tiny blocks are
// DRAIN-bound (each __syncthreads drains the global stores; 2x blocks = 2x
// drain sequences with half the work to hide them). Don't shrink further.
#define POUT_STRIDE 328
__global__ __launch_bounds__(256, 2)
void proj_kernel(const float* __restrict__ HU, const float* __restrict__ HI,
                 const unsigned short* __restrict__ wsmat,
                 const float* __restrict__ b1, const float* __restrict__ bg1,
                 uint8_t* __restrict__ PU8, uint8_t* __restrict__ PI8,
                 unsigned short* __restrict__ PGU, unsigned short* __restrict__ PGI,
                 unsigned short* __restrict__ HU16, unsigned short* __restrict__ HI16,
                 int nu, int ni, int nbu) {
    // aliased: phase A = bf16 input tile [32][128] swz256 (8KB); phase B = out [32][328] (21KB)
    __shared__ __align__(16) unsigned short lds[32 * POUT_STRIDE];
    const int t = threadIdx.x, w = t >> 6, l = t & 63, l15 = l & 15, l4 = l >> 4;
    const bool isU = (int)blockIdx.x < nbu;
    const int rb = (isU ? (int)blockIdx.x : (int)blockIdx.x - nbu) * 32;
    const int rows = isU ? nu : ni;
    const float* H = isU ? HU : HI;
    const unsigned short* Bmat = wsmat + (isU ? OFF_BU_E : OFF_BI_E);
    uint8_t* P8 = isU ? PU8 : PI8;
    unsigned short* Pg  = isU ? PGU : PGI;
    unsigned short* H16 = isU ? HU16 : HI16;
    const int addBias = isU ? 1 : 0;

    {
        const int r = t >> 3, q = t & 7;   // 8 threads/row, 16 floats each
        int rg = rb + r; int rc = rg < rows ? rg : rows - 1;
        const float* p = H + (size_t)rc * 128 + q * 16;
        f32x4 f0 = *(const f32x4*)(p);     f32x4 f1 = *(const f32x4*)(p + 4);
        f32x4 f2 = *(const f32x4*)(p + 8); f32x4 f3 = *(const f32x4*)(p + 12);
        bf16x8 h0, h1;
        #pragma unroll
        for (int j = 0; j < 4; ++j) {
            h0[j] = (__bf16)f0[j]; h0[j + 4] = (__bf16)f1[j];
            h1[j] = (__bf16)f2[j]; h1[j + 4] = (__bf16)f3[j];
        }
        *(bf16x8*)((char*)lds + swz(r, q * 16, 256)) = h0;
        *(bf16x8*)((char*)lds + swz(r, q * 16 + 8, 256)) = h1;
        if (rg < rows) {
            *(bf16x8*)(H16 + (size_t)rg * 128 + q * 16) = h0;
            *(bf16x8*)(H16 + (size_t)rg * 128 + q * 16 + 8) = h1;
        }
    }
    __syncthreads();
    // GEMM: M=32, K=128, N=320. Wave w -> cols w*80..+79 (5 n-tiles), rows 0..31 (2 m-tiles)
    f32x4 acc[2][5] = {};
    #pragma unroll
    for (int kt = 0; kt < 4; ++kt) {
        bf16x8 aA = *(const bf16x8*)((const char*)lds + swz(l15, kt * 32 + l4 * 8, 256));
        bf16x8 aB = *(const bf16x8*)((const char*)lds + swz(16 + l15, kt * 32 + l4 * 8, 256));
        #pragma unroll
        for (int nt = 0; nt < 5; ++nt) {
            const int n = w * 80 + nt * 16 + l15;
            bf16x8 bfr = *(const bf16x8*)(Bmat + n * 128 + kt * 32 + l4 * 8);
            acc[0][nt] = __builtin_amdgcn_mfma_f32_16x16x32_bf16(aA, bfr, acc[0][nt], 0, 0, 0);
            acc[1][nt] = __builtin_amdgcn_mfma_f32_16x16x32_bf16(aB, bfr, acc[1][nt], 0, 0, 0);
        }
    }
    __syncthreads();   // input-tile reads done; reuse lds as output stage
    #pragma unroll
    for (int nt = 0; nt < 5; ++nt) {
        const int n = w * 80 + nt * 16 + l15;
        const float bias = addBias ? ((n < 256) ? b1[n] : bg1[n - 256]) : 0.f;
        #pragma unroll
        for (int mt = 0; mt < 2; ++mt) {
            #pragma unroll
            for (int j = 0; j < 4; ++j) {
                const int row = mt * 16 + l4 * 4 + j;
                lds[row * POUT_STRIDE + n] = f2bf_bits(acc[mt][nt][j] + bias);  // NO relu here
            }
        }
    }
    __syncthreads();
    {
        const int r = t >> 3, q = t & 7;
        const int rg = rb + r;
        if (rg < rows) {
            uint32_t dw[8];
            #pragma unroll
            for (int vb = 0; vb < 4; ++vb) {
                bf16x8 pv = *(const bf16x8*)(&lds[r * POUT_STRIDE + q * 32 + vb * 8]);
                float f[8];
                #pragma unroll
                for (int j = 0; j < 8; ++j) f[j] = bf2f(pv[j]);
                uint32_t d0 = 0, d1 = 0;
                d0 = __builtin_amdgcn_cvt_pk_fp8_f32(f[0], f[1], d0, false);
                d0 = __builtin_amdgcn_cvt_pk_fp8_f32(f[2], f[3], d0, true);
                d1 = __builtin_amdgcn_cvt_pk_fp8_f32(f[4], f[5], d1, false);
                d1 = __builtin_amdgcn_cvt_pk_fp8_f32(f[6], f[7], d1, true);
                dw[vb * 2] = d0; dw[vb * 2 + 1] = d1;
            }
            u32x4 s0 = {dw[0], dw[1], dw[2], dw[3]};
            u32x4 s1 = {dw[4], dw[5], dw[6], dw[7]};
            *(u32x4*)(P8 + (size_t)rg * 256 + q * 32)      = s0;
            *(u32x4*)(P8 + (size_t)rg * 256 + q * 32 + 16) = s1;
            bf16x8 gv = *(const bf16x8*)(&lds[r * POUT_STRIDE + 256 + q * 8]);
            *(bf16x8*)(Pg + (size_t)rg * 64 + q * 8) = gv;
        }
    }
}

#define GRID_MAIN 2048   // 256-thr persistent blocks

// Persistent main kernel, 256 threads / 4 waves, ETILE=32 — round-11/12 (best: 146us).
// 3 barriers/iter; parity double-buffer removes sync4 (the only barrier whose
// vmcnt drain waited on the out[] store). Round-9 lesson: no asm barriers.
// Round-10 lesson: keep phase3 spread over all 4 waves.
__global__ __launch_bounds__(256, 2)
void edge_main(const int* __restrict__ src, const int* __restrict__ dst,
               const uint8_t* __restrict__ PU8, const uint8_t* __restrict__ PI8,
               const unsigned short* __restrict__ PGU, const unsigned short* __restrict__ PGI,
               const unsigned short* __restrict__ HU16, const unsigned short* __restrict__ HI16,
               const unsigned short* __restrict__ W2T, const unsigned short* __restrict__ W3T,
               const float* __restrict__ b2, const float* __restrict__ b3,
               const float* __restrict__ b4, const float* __restrict__ W4,
               const float* __restrict__ Wg2, const float* __restrict__ bg2,
               float* __restrict__ out, int E) {
    __shared__ __align__(16) unsigned short lds_x1[32 * 256];  // 16KB, swz 512
    __shared__ __align__(16) unsigned short lds_x2[32 * 128];  // 8KB, swz 256
    __shared__ float lds_dot[2][32], lds_g0[2][32], lds_g1[2][32];  // parity dbuf
    __shared__ float lds_mlp[2][4][32];
    __shared__ float lds_wg0[64], lds_wg1[64];                 // Wg2 columns (512B)

    const int t = threadIdx.x, w = t >> 6, l = t & 63, l15 = l & 15, l4 = l >> 4;
    const int r = t >> 3, q = t & 7;        // gather roles: edge slot r (0..31), chunk q

    // per-wave column bases: x2 -> cols w*32..+31 ; x3 -> cols w*16..+15
    const unsigned short* w2p = W2T + (w * 32 + l15) * 256 + l4 * 8;   // nt=1 adds 16*256
    const unsigned short* w3p = W3T + (w * 16 + l15) * 128 + l4 * 8;
    float b2v[2];
    #pragma unroll
    for (int nt = 0; nt < 2; ++nt) b2v[nt] = b2[w * 32 + nt * 16 + l15];
    const float b3v = b3[w * 16 + l15], w4v = W4[w * 16 + l15];
    const float bg2_0 = bg2[0], bg2_1 = bg2[1], b4_0 = b4[0];

    if (t < 64) { lds_wg0[t] = Wg2[t * 2]; lds_wg1[t] = Wg2[t * 2 + 1]; }

    const int NT = (E + 31) >> 5;
    int tile = blockIdx.x;
    if (tile >= NT) return;

    u32x4 gpu8[2], gpi8[2];
    bf16x8 ghu[2], ghi[2], gpg_u, gpg_i;
#define ISSUE(TT) do { \
        int e_ = (TT) * 32 + r; if (e_ >= E) e_ = E - 1; \
        const int sA_ = src[e_], dA_ = dst[e_]; \
        const uint8_t* pu_ = PU8 + (size_t)sA_ * 256 + q * 32; \
        const uint8_t* pi_ = PI8 + (size_t)dA_ * 256 + q * 32; \
        const unsigned short* hu_ = HU16 + (size_t)sA_ * 128 + q * 16; \
        const unsigned short* hi_ = HI16 + (size_t)dA_ * 128 + q * 16; \
        gpu8[0] = *(const u32x4*)(pu_);      gpu8[1] = *(const u32x4*)(pu_ + 16); \
        gpi8[0] = *(const u32x4*)(pi_);      gpi8[1] = *(const u32x4*)(pi_ + 16); \
        ghu[0] = *(const bf16x8*)(hu_);      ghu[1] = *(const bf16x8*)(hu_ + 8); \
        ghi[0] = *(const bf16x8*)(hi_);      ghi[1] = *(const bf16x8*)(hi_ + 8); \
        gpg_u = *(const bf16x8*)(PGU + (size_t)sA_ * 64 + q * 8); \
        gpg_i = *(const bf16x8*)(PGI + (size_t)dA_ * 64 + q * 8); \
    } while (0)

    ISSUE(tile);
    __syncthreads();   // prologue: lds_wg ready

    int pb = 0;
    for (;;) {
        // ---- phase 1: x1 = relu(fp8(P_u)+fp8(P_i)) -> LDS bf16; dot; gates -> [pb]
        #pragma unroll
        for (int v = 0; v < 2; ++v) {
            #pragma unroll
            for (int h = 0; h < 2; ++h) {
                bf16x8 o;
                #pragma unroll
                for (int d = 0; d < 2; ++d) {
                    const uint32_t du = gpu8[v][2 * h + d], di = gpi8[v][2 * h + d];
                    f32x2 a0 = __builtin_amdgcn_cvt_pk_f32_fp8(du, false);
                    f32x2 a1 = __builtin_amdgcn_cvt_pk_f32_fp8(du, true);
                    f32x2 c0 = __builtin_amdgcn_cvt_pk_f32_fp8(di, false);
                    f32x2 c1 = __builtin_amdgcn_cvt_pk_f32_fp8(di, true);
                    o[d * 4 + 0] = (__bf16)fmaxf(a0[0] + c0[0], 0.f);
                    o[d * 4 + 1] = (__bf16)fmaxf(a0[1] + c0[1], 0.f);
                    o[d * 4 + 2] = (__bf16)fmaxf(a1[0] + c1[0], 0.f);
                    o[d * 4 + 3] = (__bf16)fmaxf(a1[1] + c1[1], 0.f);
                }
                *(bf16x8*)((char*)lds_x1 + swz(r, q * 32 + v * 16 + h * 8, 512)) = o;
            }
        }
        {
            float dacc = 0.f;
            #pragma unroll
            for (int v = 0; v < 2; ++v)
                #pragma unroll
                for (int j = 0; j < 8; ++j)
                    dacc += bf2f(ghu[v][j]) * bf2f(ghi[v][j]);
            dacc += __shfl_xor(dacc, 1); dacc += __shfl_xor(dacc, 2); dacc += __shfl_xor(dacc, 4);
            f32x4 wg0a = *(const f32x4*)(&lds_wg0[q * 8]);
            f32x4 wg0b = *(const f32x4*)(&lds_wg0[q * 8 + 4]);
            f32x4 wg1a = *(const f32x4*)(&lds_wg1[q * 8]);
            f32x4 wg1b = *(const f32x4*)(&lds_wg1[q * 8 + 4]);
            float g0 = 0.f, g1 = 0.f;
            #pragma unroll
            for (int i = 0; i < 4; ++i) {
                float va = fmaxf(bf2f(gpg_u[i]) + bf2f(gpg_i[i]), 0.f);
                float vb = fmaxf(bf2f(gpg_u[i + 4]) + bf2f(gpg_i[i + 4]), 0.f);
                g0 += va * wg0a[i] + vb * wg0b[i];
                g1 += va * wg1a[i] + vb * wg1b[i];
            }
            g0 += __shfl_xor(g0, 1); g0 += __shfl_xor(g0, 2); g0 += __shfl_xor(g0, 4);
            g1 += __shfl_xor(g1, 1); g1 += __shfl_xor(g1, 2); g1 += __shfl_xor(g1, 4);
            if (q == 0) { lds_dot[pb][r] = dacc; lds_g0[pb][r] = g0; lds_g1[pb][r] = g1; }
        }
        __syncthreads();   // sync1: x1/dot/gates visible

        const int ntile = tile + GRID_MAIN;
        const bool hn = ntile < NT;
        if (hn) ISSUE(ntile);   // T14 prefetch; drains at sync2 (cover = phase 2)

        // ---- phase 2: x2 = relu(x1 @ W2 + b2): 32 rows, wave w -> cols w*32..+31
        {
            f32x4 acc2[2][2] = {};
            #pragma unroll
            for (int kt = 0; kt < 8; ++kt) {
                bf16x8 aA = *(const bf16x8*)((const char*)lds_x1 + swz(l15, kt * 32 + l4 * 8, 512));
                bf16x8 aB = *(const bf16x8*)((const char*)lds_x1 + swz(16 + l15, kt * 32 + l4 * 8, 512));
                bf16x8 bf0 = *(const bf16x8*)(w2p + kt * 32);
                bf16x8 bf1 = *(const bf16x8*)(w2p + 16 * 256 + kt * 32);
                acc2[0][0] = __builtin_amdgcn_mfma_f32_16x16x32_bf16(aA, bf0, acc2[0][0], 0, 0, 0);
                acc2[1][0] = __builtin_amdgcn_mfma_f32_16x16x32_bf16(aB, bf0, acc2[1][0], 0, 0, 0);
                acc2[0][1] = __builtin_amdgcn_mfma_f32_16x16x32_bf16(aA, bf1, acc2[0][1], 0, 0, 0);
                acc2[1][1] = __builtin_amdgcn_mfma_f32_16x16x32_bf16(aB, bf1, acc2[1][1], 0, 0, 0);
            }
            #pragma unroll
            for (int mt = 0; mt < 2; ++mt)
                #pragma unroll
                for (int nt = 0; nt < 2; ++nt) {
                    const int col = w * 32 + nt * 16 + l15;
                    #pragma unroll
                    for (int j = 0; j < 4; ++j) {
                        const int row = mt * 16 + l4 * 4 + j;
                        float v = fmaxf(acc2[mt][nt][j] + b2v[nt], 0.f);
                        *(unsigned short*)((char*)lds_x2 + swz(row, col, 256)) = f2bf_bits(v);
                    }
                }
        }
        __syncthreads();   // sync2: x2 ready; x1 free

        // ---- phase 3: x3 = relu(x2 @ W3 + b3), fused W4 head: wave w -> cols w*16..+15
        {
            f32x4 acc3[2] = {};
            #pragma unroll
            for (int kt = 0; kt < 4; ++kt) {
                bf16x8 a0 = *(const bf16x8*)((const char*)lds_x2 + swz(l15, kt * 32 + l4 * 8, 256));
                bf16x8 a1 = *(const bf16x8*)((const char*)lds_x2 + swz(16 + l15, kt * 32 + l4 * 8, 256));
                bf16x8 bfr = *(const bf16x8*)(w3p + kt * 32);
                acc3[0] = __builtin_amdgcn_mfma_f32_16x16x32_bf16(a0, bfr, acc3[0], 0, 0, 0);
                acc3[1] = __builtin_amdgcn_mfma_f32_16x16x32_bf16(a1, bfr, acc3[1], 0, 0, 0);
            }
            float mp[2][4];
            #pragma unroll
            for (int mt = 0; mt < 2; ++mt)
                #pragma unroll
                for (int j = 0; j < 4; ++j) {
                    mp[mt][j] = fmaxf(acc3[mt][j] + b3v, 0.f) * w4v;
                    mp[mt][j] += __shfl_xor(mp[mt][j], 1);
                    mp[mt][j] += __shfl_xor(mp[mt][j], 2);
                    mp[mt][j] += __shfl_xor(mp[mt][j], 4);
                    mp[mt][j] += __shfl_xor(mp[mt][j], 8);
                }
            if (l15 == 0) {
                #pragma unroll
                for (int mt = 0; mt < 2; ++mt)
                    #pragma unroll
                    for (int j = 0; j < 4; ++j)
                        lds_mlp[pb][w][mt * 16 + l4 * 4 + j] = mp[mt][j];
            }
        }
        __syncthreads();   // sync3: mlp partials ready

        if (t < 32) {
            const int e = tile * 32 + t;
            if (e < E) {
                const float mlp = lds_mlp[pb][0][t] + lds_mlp[pb][1][t] + lds_mlp[pb][2][t]
                                + lds_mlp[pb][3][t] + b4_0;
                const float dot = lds_dot[pb][t];
                const float L0 = lds_g0[pb][t] + bg2_0, L1 = lds_g1[pb][t] + bg2_1;
                const float d = L1 - L0;
                const float z = __expf(-fabsf(d));
                const float inv = 1.f / (1.f + z);
                const float g1s = (d >= 0.f) ? inv : z * inv;
                out[e] = (1.f - g1s) * dot + g1s * mlp;
            }
        }
        // no sync4: parity buffers make the next iteration's writes hazard-free
        if (!hn) break;
        tile = ntile;
        pb ^= 1;
    }
#undef ISSUE
}

// ===================== FALLBACK (used only if ws too small) =====================
#define FB_ETILE 128
#define FB_WT1_OFF 0
#define FB_WT2_OFF 65536
#define FB_WT3_OFF 98304
#define FB_WTG1_OFF 106496
#define FB_WTOT 122880

__global__ void prep_weights_fb(const float* __restrict__ W1, const float* __restrict__ W2,
                                const float* __restrict__ W3, const float* __restrict__ Wg1,
                                unsigned short* __restrict__ ws) {
    int idx = blockIdx.x * 256 + threadIdx.x;
    if (idx >= FB_WTOT) return;
    float v;
    if (idx < FB_WT2_OFF)      { int n = idx >> 8, k = idx & 255; v = W1[k * 256 + n]; }
    else if (idx < FB_WT3_OFF) { int loc = idx - FB_WT2_OFF; int n = loc >> 8, k = loc & 255; v = W2[k * 128 + n]; }
    else if (idx < FB_WTG1_OFF){ int loc = idx - FB_WT3_OFF; int n = loc >> 7, k = loc & 127; v = W3[k * 64 + n]; }
    else                       { int loc = idx - FB_WTG1_OFF; int n = loc >> 8, k = loc & 255; v = Wg1[k * 64 + n]; }
    ws[idx] = f2bf_bits(v);
}

__global__ __launch_bounds__(512, 2)
void fused_edge_kernel_fb(const float* __restrict__ h_user, const float* __restrict__ h_item,
                          const int* __restrict__ src, const int* __restrict__ dst,
                          const unsigned short* __restrict__ wsmat,
                          const float* __restrict__ b1, const float* __restrict__ b2,
                          const float* __restrict__ b3, const float* __restrict__ b4,
                          const float* __restrict__ W4, const float* __restrict__ bg1,
                          const float* __restrict__ Wg2, const float* __restrict__ bg2,
                          float* __restrict__ out, int E) {
    __shared__ __align__(16) unsigned short lds_e[FB_ETILE * 256];
    __shared__ __align__(16) unsigned short lds_x1[FB_ETILE * 256];
    __shared__ float lds_dot[FB_ETILE];
    const unsigned short* wt1  = wsmat + FB_WT1_OFF;
    const unsigned short* wt2  = wsmat + FB_WT2_OFF;
    const unsigned short* wt3  = wsmat + FB_WT3_OFF;
    const unsigned short* wtg1 = wsmat + FB_WTG1_OFF;
    const int t = threadIdx.x, eb = blockIdx.x * FB_ETILE;
    const int w = t >> 6, l = t & 63, l15 = l & 15, l4 = l >> 4;
    {
        const int r = t >> 2, q = t & 3;
        int e = eb + r; if (e >= E) e = E - 1;
        const int idx = (q < 2) ? src[e] : dst[e];
        const float* rowp = ((q < 2) ? h_user : h_item) + (size_t)idx * 128 + (q & 1) * 64;
        const uint32_t cbase = (uint32_t)q * 64u;
        #pragma unroll
        for (int i = 0; i < 8; ++i) {
            f32x4 a = *reinterpret_cast<const f32x4*>(rowp + i * 8);
            f32x4 b = *reinterpret_cast<const f32x4*>(rowp + i * 8 + 4);
            bf16x8 p;
            #pragma unroll
            for (int j = 0; j < 4; ++j) { p[j] = (__bf16)a[j]; p[j + 4] = (__bf16)b[j]; }
            *reinterpret_cast<bf16x8*>((char*)lds_e + swz(r, cbase + i * 8u, 512)) = p;
        }
    }
    __syncthreads();
    {
        const int r = t >> 2, q = t & 3;
        float acc = 0.f;
        #pragma unroll
        for (int i = 0; i < 4; ++i) {
            uint32_t c = (uint32_t)q * 32u + i * 8u;
            bf16x8 sv = *reinterpret_cast<const bf16x8*>((const char*)lds_e + swz(r, c, 512));
            bf16x8 dv = *reinterpret_cast<const bf16x8*>((const char*)lds_e + swz(r, 128u + c, 512));
            #pragma unroll
            for (int j = 0; j < 8; ++j) acc += (float)sv[j] * (float)dv[j];
        }
        acc += __shfl_xor(acc, 1); acc += __shfl_xor(acc, 2);
        if (q == 0) lds_dot[r] = acc;
    }
    {
        const int mg = w >> 2, cg = w & 3;
        f32x4 acc[4][4] = {};
        #pragma unroll
        for (int kh = 0; kh < 2; ++kh) {
            bf16x8 afr[4][4];
            #pragma unroll
            for (int mt = 0; mt < 4; ++mt)
                #pragma unroll
                for (int kt = 0; kt < 4; ++kt)
                    afr[mt][kt] = *reinterpret_cast<const bf16x8*>((const char*)lds_e +
                        swz(mg * 64 + mt * 16 + l15, kh * 128 + kt * 32 + l4 * 8, 512));
            #pragma unroll
            for (int nt = 0; nt < 4; ++nt) {
                const int n = cg * 64 + nt * 16 + l15;
                #pragma unroll
                for (int kt = 0; kt < 4; ++kt) {
                    bf16x8 bfr = *reinterpret_cast<const bf16x8*>(wt1 + n * 256 + kh * 128 + kt * 32 + l4 * 8);
                    #pragma unroll
                    for (int mt = 0; mt < 4; ++mt)
                        acc[mt][nt] = __builtin_amdgcn_mfma_f32_16x16x32_bf16(afr[mt][kt], bfr, acc[mt][nt], 0, 0, 0);
                }
            }
        }
        #pragma unroll
        for (int nt = 0; nt < 4; ++nt) {
            const int col = cg * 64 + nt * 16 + l15;
            const float bias = b1[col];
            #pragma unroll
            for (int mt = 0; mt < 4; ++mt) {
                const int row0 = mg * 64 + mt * 16 + l4 * 4;
                #pragma unroll
                for (int j = 0; j < 4; ++j) {
                    float v = fmaxf(acc[mt][nt][j] + bias, 0.f);
                    *reinterpret_cast<unsigned short*>((char*)lds_x1 + swz(row0 + j, col, 512)) = f2bf_bits(v);
                }
            }
        }
    }
    float l0p[4] = {0, 0, 0, 0}, l1p[4] = {0, 0, 0, 0};
    {
        bf16x8 ag[8];
        #pragma unroll
        for (int kt = 0; kt < 8; ++kt)
            ag[kt] = *reinterpret_cast<const bf16x8*>((const char*)lds_e + swz(w * 16 + l15, kt * 32 + l4 * 8, 512));
        f32x4 accg[4] = {};
        #pragma unroll
        for (int nt = 0; nt < 4; ++nt) {
            const int n = nt * 16 + l15;
            #pragma unroll
            for (int kt = 0; kt < 8; ++kt) {
                bf16x8 bfr = *reinterpret_cast<const bf16x8*>(wtg1 + n * 256 + kt * 32 + l4 * 8);
                accg[nt] = __builtin_amdgcn_mfma_f32_16x16x32_bf16(ag[kt], bfr, accg[nt], 0, 0, 0);
            }
        }
        #pragma unroll
        for (int nt = 0; nt < 4; ++nt) {
            const int col = nt * 16 + l15;
            const float bg = bg1[col];
            const float w0 = Wg2[col * 2 + 0], w1 = Wg2[col * 2 + 1];
            #pragma unroll
            for (int j = 0; j < 4; ++j) {
                float v = fmaxf(accg[nt][j] + bg, 0.f);
                l0p[j] += v * w0; l1p[j] += v * w1;
            }
        }
        #pragma unroll
        for (int j = 0; j < 4; ++j)
            #pragma unroll
            for (int m = 1; m < 16; m <<= 1) {
                l0p[j] += __shfl_xor(l0p[j], m);
                l1p[j] += __shfl_xor(l1p[j], m);
            }
    }
    __syncthreads();
    {
        const int mg = w >> 1, cg = w & 1;
        bf16x8 a2[2][8];
        #pragma unroll
        for (int mt = 0; mt < 2; ++mt)
            #pragma unroll
            for (int kt = 0; kt < 8; ++kt)
                a2[mt][kt] = *reinterpret_cast<const bf16x8*>((const char*)lds_x1 +
                    swz(mg * 32 + mt * 16 + l15, kt * 32 + l4 * 8, 512));
        f32x4 acc2[2][4] = {};
        #pragma unroll
        for (int nt = 0; nt < 4; ++nt) {
            const int n = cg * 64 + nt * 16 + l15;
            #pragma unroll
            for (int kt = 0; kt < 8; ++kt) {
                bf16x8 bfr = *reinterpret_cast<const bf16x8*>(wt2 + n * 256 + kt * 32 + l4 * 8);
                #pragma unroll
                for (int mt = 0; mt < 2; ++mt)
                    acc2[mt][nt] = __builtin_amdgcn_mfma_f32_16x16x32_bf16(a2[mt][kt], bfr, acc2[mt][nt], 0, 0, 0);
            }
        }
        #pragma unroll
        for (int nt = 0; nt < 4; ++nt) {
            const int col = cg * 64 + nt * 16 + l15;
            const float bias = b2[col];
            #pragma unroll
            for (int mt = 0; mt < 2; ++mt) {
                const int row0 = mg * 32 + mt * 16 + l4 * 4;
                #pragma unroll
                for (int j = 0; j < 4; ++j) {
                    float v = fmaxf(acc2[mt][nt][j] + bias, 0.f);
                    *reinterpret_cast<unsigned short*>((char*)lds_e + swz(row0 + j, col, 256)) = f2bf_bits(v);
                }
            }
        }
    }
    __syncthreads();
    {
        float mlpp[4] = {0, 0, 0, 0};
        bf16x8 a3[4];
        #pragma unroll
        for (int kt = 0; kt < 4; ++kt)
            a3[kt] = *reinterpret_cast<const bf16x8*>((const char*)lds_e + swz(w * 16 + l15, kt * 32 + l4 * 8, 256));
        f32x4 acc3[4] = {};
        #pragma unroll
        for (int nt = 0; nt < 4; ++nt) {
            const int n = nt * 16 + l15;
            #pragma unroll
            for (int kt = 0; kt < 4; ++kt) {
                bf16x8 bfr = *reinterpret_cast<const bf16x8*>(wt3 + n * 128 + kt * 32 + l4 * 8);
                acc3[nt] = __builtin_amdgcn_mfma_f32_16x16x32_bf16(a3[kt], bfr, acc3[nt], 0, 0, 0);
            }
        }
        #pragma unroll
        for (int nt = 0; nt < 4; ++nt) {
            const int col = nt * 16 + l15;
            const float b3v = b3[col];
            const float w4v = W4[col];
            #pragma unroll
            for (int j = 0; j < 4; ++j) {
                float v = fmaxf(acc3[nt][j] + b3v, 0.f);
                mlpp[j] += v * w4v;
            }
        }
        #pragma unroll
        for (int j = 0; j < 4; ++j)
            #pragma unroll
            for (int m = 1; m < 16; m <<= 1)
                mlpp[j] += __shfl_xor(mlpp[j], m);
        if (l15 == 0) {
            #pragma unroll
            for (int j = 0; j < 4; ++j) {
                const int rr = w * 16 + l4 * 4 + j;
                const int e = eb + rr;
                if (e < E) {
                    const float dot = lds_dot[rr];
                    const float mlp = mlpp[j] + b4[0];
                    const float L0 = l0p[j] + bg2[0];
                    const float L1 = l1p[j] + bg2[1];
                    const float d = L1 - L0;
                    const float z = __expf(-fabsf(d));
                    const float inv = 1.f / (1.f + z);
                    const float g1 = (d >= 0.f) ? inv : z * inv;
                    out[e] = (1.f - g1) * dot + g1 * mlp;
                }
            }
        }
    }
}

// ===================== launch =====================
extern "C" void kernel_launch(void* const* d_in, const int* in_sizes, int n_in,
                              void* d_out, int out_size, void* d_ws, size_t ws_size,
                              hipStream_t stream) {
    const float* h_user = (const float*)d_in[0];
    const float* h_item = (const float*)d_in[1];
    const int*   src    = (const int*)d_in[2];
    const int*   dst    = (const int*)d_in[3];
    const float* W1  = (const float*)d_in[4];
    const float* b1  = (const float*)d_in[5];
    const float* W2  = (const float*)d_in[6];
    const float* b2  = (const float*)d_in[7];
    const float* W3  = (const float*)d_in[8];
    const float* b3  = (const float*)d_in[9];
    const float* W4  = (const float*)d_in[10];
    const float* b4  = (const float*)d_in[11];
    const float* Wg1 = (const float*)d_in[12];
    const float* bg1 = (const float*)d_in[13];
    const float* Wg2 = (const float*)d_in[14];
    const float* bg2 = (const float*)d_in[15];
    const int E  = in_sizes[2];
    const int nu = in_sizes[0] / 128;
    const int ni = in_sizes[1] / 128;

    unsigned short* ws = (unsigned short*)d_ws;
    char* wsb = (char*)d_ws;

    // fast-path table layout (byte offsets past the bf16 weight blob)
    size_t off = OFF_TBL_B;
    uint8_t* PU8 = (uint8_t*)(wsb + off); off += (size_t)nu * 256;
    uint8_t* PI8 = (uint8_t*)(wsb + off); off += (size_t)ni * 256;
    unsigned short* PGU  = (unsigned short*)(wsb + off); off += (size_t)nu * 128;
    unsigned short* PGI  = (unsigned short*)(wsb + off); off += (size_t)ni * 128;
    unsigned short* HU16 = (unsigned short*)(wsb + off); off += (size_t)nu * 256;
    unsigned short* HI16 = (unsigned short*)(wsb + off); off += (size_t)ni * 256;
    const size_t need_bytes = off;

    if (ws_size >= need_bytes) {
        prep_weights_fast<<<(PREP_TOT + 255) / 256, 256, 0, stream>>>(W1, Wg1, W2, W3, ws);
        const int nbu = (nu + 31) / 32, nbi = (ni + 31) / 32;
        proj_kernel<<<nbu + nbi, 256, 0, stream>>>(h_user, h_item, ws, b1, bg1,
                                                   PU8, PI8, PGU, PGI, HU16, HI16, nu, ni, nbu);
        edge_main<<<GRID_MAIN, 256, 0, stream>>>(src, dst, PU8, PI8, PGU, PGI, HU16, HI16,
                                                 ws + OFF_W2T_E, ws + OFF_W3T_E,
                                                 b2, b3, b4, W4, Wg2, bg2, (float*)d_out, E);
    } else {
        prep_weights_fb<<<(FB_WTOT + 255) / 256, 256, 0, stream>>>(W1, W2, W3, Wg1, ws);
        const int nblk = (E + FB_ETILE - 1) / FB_ETILE;
        fused_edge_kernel_fb<<<nblk, 512, 0, stream>>>(h_user, h_item, src, dst, ws,
                                                       b1, b2, b3, b4, W4, bg1, Wg2, bg2,
                                                       (float*)d_out, E);
    }
}

// Round 15
// 198.384 us; speedup vs baseline: 1.2631x; 1.0550x over previous
//
#include <hip/hip_runtime.h>
#include <hip/hip_bf16.h>
#include <stdint.h>

typedef __bf16 bf16x8 __attribute__((ext_vector_type(8)));
typedef float f32x4 __attribute__((ext_vector_type(4)));
typedef float f32x2 __attribute__((ext_vector_type(2)));
typedef uint32_t u32x4 __attribute__((ext_vector_type(4)));

// LDS XOR swizzle (Guideline 4): spreads 8 rows across distinct 16B slots.
__device__ __forceinline__ uint32_t swz(uint32_t row, uint32_t col, uint32_t strideB) {
    return (row * strideB + col * 2u) ^ ((row & 7u) << 4);
}
__device__ __forceinline__ unsigned short f2bf_bits(float v) {
    __bf16 h = (__bf16)v; return __builtin_bit_cast(unsigned short, h);
}
__device__ __forceinline__ float bf2f(__bf16 h) { return (float)h; }

// ===================== FAST PATH =====================
// ws element offsets (ushort) for weight blobs
#define OFF_BU_E    0         // [320][128]  (W1u | Wg1u)^T
#define OFF_BI_E    40960     // [320][128]  (W1i | Wg1i)^T
#define OFF_W2T_E   81920     // [128][256]  W2^T
#define OFF_W3T_E   114688    // [64][128]   W3^T
#define PREP_TOT    122880
#define OFF_TBL_B   262144    // tables start (byte offset)

__global__ void prep_weights_fast(const float* __restrict__ W1, const float* __restrict__ Wg1,
                                  const float* __restrict__ W2, const float* __restrict__ W3,
                                  unsigned short* __restrict__ ws) {
    int idx = blockIdx.x * 256 + threadIdx.x;
    if (idx >= PREP_TOT) return;
    float v;
    if (idx < OFF_BI_E) {                       // Bu[n][k] = W1[k][n] or Wg1[k][n-256], k user rows
        int n = idx >> 7, k = idx & 127;
        v = (n < 256) ? W1[k * 256 + n] : Wg1[k * 64 + (n - 256)];
    } else if (idx < OFF_W2T_E) {               // Bi: item rows k+128
        int loc = idx - OFF_BI_E; int n = loc >> 7, k = loc & 127;
        v = (n < 256) ? W1[(128 + k) * 256 + n] : Wg1[(128 + k) * 64 + (n - 256)];
    } else if (idx < OFF_W3T_E) {               // W2T [128n][256k]
        int loc = idx - OFF_W2T_E; int n = loc >> 8, k = loc & 255;
        v = W2[k * 128 + n];
    } else {                                    // W3T [64n][128k]
        int loc = idx - OFF_W3T_E; int n = loc >> 7, k = loc & 127;
        v = W3[k * 64 + n];
    }
    ws[idx] = f2bf_bits(v);
}

// Merged dense projection (user blocks then item blocks):
// [P | Pg](+bias for user) = H @ Bmat^T; also emits bf16 copy of H.
// P stored as fp8 e4m3 (MLP trunk tolerates ~6% rel err; dot/gate paths stay bf16).
// 32-row / 256-thread blocks = measured optimum (round-12: ~56us).
// Round-13 lesson: 16-row blocks regressed 56->146us — tiny blocks are
// DRAIN-bound (each __syncthreads drains the global stores; 2x blocks = 2x
// drain sequences with half the work to hide them). Don't shrink further.
#define POUT_STRIDE 328
__global__ __launch_bounds__(256, 2)
void proj_kernel(const float* __restrict__ HU, const float* __restrict__ HI,
                 const unsigned short* __restrict__ wsmat,
                 const float* __restrict__ b1, const float* __restrict__ bg1,
                 uint8_t* __restrict__ PU8, uint8_t* __restrict__ PI8,
                 unsigned short* __restrict__ PGU, unsigned short* __restrict__ PGI,
                 unsigned short* __restrict__ HU16, unsigned short* __restrict__ HI16,
                 int nu, int ni, int nbu) {
    // aliased: phase A = bf16 input tile [32][128] swz256 (8KB); phase B = out [32][328] (21KB)
    __shared__ __align__(16) unsigned short lds[32 * POUT_STRIDE];
    const int t = threadIdx.x, w = t >> 6, l = t & 63, l15 = l & 15, l4 = l >> 4;
    const bool isU = (int)blockIdx.x < nbu;
    const int rb = (isU ? (int)blockIdx.x : (int)blockIdx.x - nbu) * 32;
    const int rows = isU ? nu : ni;
    const float* H = isU ? HU : HI;
    const unsigned short* Bmat = wsmat + (isU ? OFF_BU_E : OFF_BI_E);
    uint8_t* P8 = isU ? PU8 : PI8;
    unsigned short* Pg  = isU ? PGU : PGI;
    unsigned short* H16 = isU ? HU16 : HI16;
    const int addBias = isU ? 1 : 0;

    {
        const int r = t >> 3, q = t & 7;   // 8 threads/row, 16 floats each
        int rg = rb + r; int rc = rg < rows ? rg : rows - 1;
        const float* p = H + (size_t)rc * 128 + q * 16;
        f32x4 f0 = *(const f32x4*)(p);     f32x4 f1 = *(const f32x4*)(p + 4);
        f32x4 f2 = *(const f32x4*)(p + 8); f32x4 f3 = *(const f32x4*)(p + 12);
        bf16x8 h0, h1;
        #pragma unroll
        for (int j = 0; j < 4; ++j) {
            h0[j] = (__bf16)f0[j]; h0[j + 4] = (__bf16)f1[j];
            h1[j] = (__bf16)f2[j]; h1[j + 4] = (__bf16)f3[j];
        }
        *(bf16x8*)((char*)lds + swz(r, q * 16, 256)) = h0;
        *(bf16x8*)((char*)lds + swz(r, q * 16 + 8, 256)) = h1;
        if (rg < rows) {
            *(bf16x8*)(H16 + (size_t)rg * 128 + q * 16) = h0;
            *(bf16x8*)(H16 + (size_t)rg * 128 + q * 16 + 8) = h1;
        }
    }
    __syncthreads();
    // GEMM: M=32, K=128, N=320. Wave w -> cols w*80..+79 (5 n-tiles), rows 0..31 (2 m-tiles)
    f32x4 acc[2][5] = {};
    #pragma unroll
    for (int kt = 0; kt < 4; ++kt) {
        bf16x8 aA = *(const bf16x8*)((const char*)lds + swz(l15, kt * 32 + l4 * 8, 256));
        bf16x8 aB = *(const bf16x8*)((const char*)lds + swz(16 + l15, kt * 32 + l4 * 8, 256));
        #pragma unroll
        for (int nt = 0; nt < 5; ++nt) {
            const int n = w * 80 + nt * 16 + l15;
            bf16x8 bfr = *(const bf16x8*)(Bmat + n * 128 + kt * 32 + l4 * 8);
            acc[0][nt] = __builtin_amdgcn_mfma_f32_16x16x32_bf16(aA, bfr, acc[0][nt], 0, 0, 0);
            acc[1][nt] = __builtin_amdgcn_mfma_f32_16x16x32_bf16(aB, bfr, acc[1][nt], 0, 0, 0);
        }
    }
    __syncthreads();   // input-tile reads done; reuse lds as output stage
    #pragma unroll
    for (int nt = 0; nt < 5; ++nt) {
        const int n = w * 80 + nt * 16 + l15;
        const float bias = addBias ? ((n < 256) ? b1[n] : bg1[n - 256]) : 0.f;
        #pragma unroll
        for (int mt = 0; mt < 2; ++mt) {
            #pragma unroll
            for (int j = 0; j < 4; ++j) {
                const int row = mt * 16 + l4 * 4 + j;
                lds[row * POUT_STRIDE + n] = f2bf_bits(acc[mt][nt][j] + bias);  // NO relu here
            }
        }
    }
    __syncthreads();
    {
        const int r = t >> 3, q = t & 7;
        const int rg = rb + r;
        if (rg < rows) {
            uint32_t dw[8];
            #pragma unroll
            for (int vb = 0; vb < 4; ++vb) {
                bf16x8 pv = *(const bf16x8*)(&lds[r * POUT_STRIDE + q * 32 + vb * 8]);
                float f[8];
                #pragma unroll
                for (int j = 0; j < 8; ++j) f[j] = bf2f(pv[j]);
                uint32_t d0 = 0, d1 = 0;
                d0 = __builtin_amdgcn_cvt_pk_fp8_f32(f[0], f[1], d0, false);
                d0 = __builtin_amdgcn_cvt_pk_fp8_f32(f[2], f[3], d0, true);
                d1 = __builtin_amdgcn_cvt_pk_fp8_f32(f[4], f[5], d1, false);
                d1 = __builtin_amdgcn_cvt_pk_fp8_f32(f[6], f[7], d1, true);
                dw[vb * 2] = d0; dw[vb * 2 + 1] = d1;
            }
            u32x4 s0 = {dw[0], dw[1], dw[2], dw[3]};
            u32x4 s1 = {dw[4], dw[5], dw[6], dw[7]};
            *(u32x4*)(P8 + (size_t)rg * 256 + q * 32)      = s0;
            *(u32x4*)(P8 + (size_t)rg * 256 + q * 32 + 16) = s1;
            bf16x8 gv = *(const bf16x8*)(&lds[r * POUT_STRIDE + 256 + q * 8]);
            *(bf16x8*)(Pg + (size_t)rg * 64 + q * 8) = gv;
        }
    }
}

#define GRID_MAIN 512   // exactly co-resident (2 blocks/CU x 256 CU): one persistent
                        // generation, one prologue, continuous prefetch chain, and tail
                        // imbalance +-1/30.5 tiles (~1.6%) vs 2048's 4 generations with
                        // +-1/7.6 (~4.8%) + 3 extra cold un-prefetched first iterations.

// Persistent main kernel, 256 threads / 4 waves, ETILE=32 — round-11/12 (best: 146us).
// 3 barriers/iter; parity double-buffer removes sync4 (the only barrier whose
// vmcnt drain waited on the out[] store). Round-9 lesson: no asm barriers.
// Round-10 lesson: keep phase3 spread over all 4 waves.
__global__ __launch_bounds__(256, 2)
void edge_main(const int* __restrict__ src, const int* __restrict__ dst,
               const uint8_t* __restrict__ PU8, const uint8_t* __restrict__ PI8,
               const unsigned short* __restrict__ PGU, const unsigned short* __restrict__ PGI,
               const unsigned short* __restrict__ HU16, const unsigned short* __restrict__ HI16,
               const unsigned short* __restrict__ W2T, const unsigned short* __restrict__ W3T,
               const float* __restrict__ b2, const float* __restrict__ b3,
               const float* __restrict__ b4, const float* __restrict__ W4,
               const float* __restrict__ Wg2, const float* __restrict__ bg2,
               float* __restrict__ out, int E) {
    __shared__ __align__(16) unsigned short lds_x1[32 * 256];  // 16KB, swz 512
    __shared__ __align__(16) unsigned short lds_x2[32 * 128];  // 8KB, swz 256
    __shared__ float lds_dot[2][32], lds_g0[2][32], lds_g1[2][32];  // parity dbuf
    __shared__ float lds_mlp[2][4][32];
    __shared__ float lds_wg0[64], lds_wg1[64];                 // Wg2 columns (512B)

    const int t = threadIdx.x, w = t >> 6, l = t & 63, l15 = l & 15, l4 = l >> 4;
    const int r = t >> 3, q = t & 7;        // gather roles: edge slot r (0..31), chunk q

    // per-wave column bases: x2 -> cols w*32..+31 ; x3 -> cols w*16..+15
    const unsigned short* w2p = W2T + (w * 32 + l15) * 256 + l4 * 8;   // nt=1 adds 16*256
    const unsigned short* w3p = W3T + (w * 16 + l15) * 128 + l4 * 8;
    float b2v[2];
    #pragma unroll
    for (int nt = 0; nt < 2; ++nt) b2v[nt] = b2[w * 32 + nt * 16 + l15];
    const float b3v = b3[w * 16 + l15], w4v = W4[w * 16 + l15];
    const float bg2_0 = bg2[0], bg2_1 = bg2[1], b4_0 = b4[0];

    if (t < 64) { lds_wg0[t] = Wg2[t * 2]; lds_wg1[t] = Wg2[t * 2 + 1]; }

    const int NT = (E + 31) >> 5;
    int tile = blockIdx.x;
    if (tile >= NT) return;

    u32x4 gpu8[2], gpi8[2];
    bf16x8 ghu[2], ghi[2], gpg_u, gpg_i;
#define ISSUE(TT) do { \
        int e_ = (TT) * 32 + r; if (e_ >= E) e_ = E - 1; \
        const int sA_ = src[e_], dA_ = dst[e_]; \
        const uint8_t* pu_ = PU8 + (size_t)sA_ * 256 + q * 32; \
        const uint8_t* pi_ = PI8 + (size_t)dA_ * 256 + q * 32; \
        const unsigned short* hu_ = HU16 + (size_t)sA_ * 128 + q * 16; \
        const unsigned short* hi_ = HI16 + (size_t)dA_ * 128 + q * 16; \
        gpu8[0] = *(const u32x4*)(pu_);      gpu8[1] = *(const u32x4*)(pu_ + 16); \
        gpi8[0] = *(const u32x4*)(pi_);      gpi8[1] = *(const u32x4*)(pi_ + 16); \
        ghu[0] = *(const bf16x8*)(hu_);      ghu[1] = *(const bf16x8*)(hu_ + 8); \
        ghi[0] = *(const bf16x8*)(hi_);      ghi[1] = *(const bf16x8*)(hi_ + 8); \
        gpg_u = *(const bf16x8*)(PGU + (size_t)sA_ * 64 + q * 8); \
        gpg_i = *(const bf16x8*)(PGI + (size_t)dA_ * 64 + q * 8); \
    } while (0)

    ISSUE(tile);
    __syncthreads();   // prologue: lds_wg ready

    int pb = 0;
    for (;;) {
        // ---- phase 1: x1 = relu(fp8(P_u)+fp8(P_i)) -> LDS bf16; dot; gates -> [pb]
        #pragma unroll
        for (int v = 0; v < 2; ++v) {
            #pragma unroll
            for (int h = 0; h < 2; ++h) {
                bf16x8 o;
                #pragma unroll
                for (int d = 0; d < 2; ++d) {
                    const uint32_t du = gpu8[v][2 * h + d], di = gpi8[v][2 * h + d];
                    f32x2 a0 = __builtin_amdgcn_cvt_pk_f32_fp8(du, false);
                    f32x2 a1 = __builtin_amdgcn_cvt_pk_f32_fp8(du, true);
                    f32x2 c0 = __builtin_amdgcn_cvt_pk_f32_fp8(di, false);
                    f32x2 c1 = __builtin_amdgcn_cvt_pk_f32_fp8(di, true);
                    o[d * 4 + 0] = (__bf16)fmaxf(a0[0] + c0[0], 0.f);
                    o[d * 4 + 1] = (__bf16)fmaxf(a0[1] + c0[1], 0.f);
                    o[d * 4 + 2] = (__bf16)fmaxf(a1[0] + c1[0], 0.f);
                    o[d * 4 + 3] = (__bf16)fmaxf(a1[1] + c1[1], 0.f);
                }
                *(bf16x8*)((char*)lds_x1 + swz(r, q * 32 + v * 16 + h * 8, 512)) = o;
            }
        }
        {
            float dacc = 0.f;
            #pragma unroll
            for (int v = 0; v < 2; ++v)
                #pragma unroll
                for (int j = 0; j < 8; ++j)
                    dacc += bf2f(ghu[v][j]) * bf2f(ghi[v][j]);
            dacc += __shfl_xor(dacc, 1); dacc += __shfl_xor(dacc, 2); dacc += __shfl_xor(dacc, 4);
            f32x4 wg0a = *(const f32x4*)(&lds_wg0[q * 8]);
            f32x4 wg0b = *(const f32x4*)(&lds_wg0[q * 8 + 4]);
            f32x4 wg1a = *(const f32x4*)(&lds_wg1[q * 8]);
            f32x4 wg1b = *(const f32x4*)(&lds_wg1[q * 8 + 4]);
            float g0 = 0.f, g1 = 0.f;
            #pragma unroll
            for (int i = 0; i < 4; ++i) {
                float va = fmaxf(bf2f(gpg_u[i]) + bf2f(gpg_i[i]), 0.f);
                float vb = fmaxf(bf2f(gpg_u[i + 4]) + bf2f(gpg_i[i + 4]), 0.f);
                g0 += va * wg0a[i] + vb * wg0b[i];
                g1 += va * wg1a[i] + vb * wg1b[i];
            }
            g0 += __shfl_xor(g0, 1); g0 += __shfl_xor(g0, 2); g0 += __shfl_xor(g0, 4);
            g1 += __shfl_xor(g1, 1); g1 += __shfl_xor(g1, 2); g1 += __shfl_xor(g1, 4);
            if (q == 0) { lds_dot[pb][r] = dacc; lds_g0[pb][r] = g0; lds_g1[pb][r] = g1; }
        }
        __syncthreads();   // sync1: x1/dot/gates visible

        const int ntile = tile + GRID_MAIN;
        const bool hn = ntile < NT;
        if (hn) ISSUE(ntile);   // T14 prefetch; drains at sync2 (cover = phase 2)

        // ---- phase 2: x2 = relu(x1 @ W2 + b2): 32 rows, wave w -> cols w*32..+31
        {
            f32x4 acc2[2][2] = {};
            #pragma unroll
            for (int kt = 0; kt < 8; ++kt) {
                bf16x8 aA = *(const bf16x8*)((const char*)lds_x1 + swz(l15, kt * 32 + l4 * 8, 512));
                bf16x8 aB = *(const bf16x8*)((const char*)lds_x1 + swz(16 + l15, kt * 32 + l4 * 8, 512));
                bf16x8 bf0 = *(const bf16x8*)(w2p + kt * 32);
                bf16x8 bf1 = *(const bf16x8*)(w2p + 16 * 256 + kt * 32);
                acc2[0][0] = __builtin_amdgcn_mfma_f32_16x16x32_bf16(aA, bf0, acc2[0][0], 0, 0, 0);
                acc2[1][0] = __builtin_amdgcn_mfma_f32_16x16x32_bf16(aB, bf0, acc2[1][0], 0, 0, 0);
                acc2[0][1] = __builtin_amdgcn_mfma_f32_16x16x32_bf16(aA, bf1, acc2[0][1], 0, 0, 0);
                acc2[1][1] = __builtin_amdgcn_mfma_f32_16x16x32_bf16(aB, bf1, acc2[1][1], 0, 0, 0);
            }
            #pragma unroll
            for (int mt = 0; mt < 2; ++mt)
                #pragma unroll
                for (int nt = 0; nt < 2; ++nt) {
                    const int col = w * 32 + nt * 16 + l15;
                    #pragma unroll
                    for (int j = 0; j < 4; ++j) {
                        const int row = mt * 16 + l4 * 4 + j;
                        float v = fmaxf(acc2[mt][nt][j] + b2v[nt], 0.f);
                        *(unsigned short*)((char*)lds_x2 + swz(row, col, 256)) = f2bf_bits(v);
                    }
                }
        }
        __syncthreads();   // sync2: x2 ready; x1 free

        // ---- phase 3: x3 = relu(x2 @ W3 + b3), fused W4 head: wave w -> cols w*16..+15
        {
            f32x4 acc3[2] = {};
            #pragma unroll
            for (int kt = 0; kt < 4; ++kt) {
                bf16x8 a0 = *(const bf16x8*)((const char*)lds_x2 + swz(l15, kt * 32 + l4 * 8, 256));
                bf16x8 a1 = *(const bf16x8*)((const char*)lds_x2 + swz(16 + l15, kt * 32 + l4 * 8, 256));
                bf16x8 bfr = *(const bf16x8*)(w3p + kt * 32);
                acc3[0] = __builtin_amdgcn_mfma_f32_16x16x32_bf16(a0, bfr, acc3[0], 0, 0, 0);
                acc3[1] = __builtin_amdgcn_mfma_f32_16x16x32_bf16(a1, bfr, acc3[1], 0, 0, 0);
            }
            float mp[2][4];
            #pragma unroll
            for (int mt = 0; mt < 2; ++mt)
                #pragma unroll
                for (int j = 0; j < 4; ++j) {
                    mp[mt][j] = fmaxf(acc3[mt][j] + b3v, 0.f) * w4v;
                    mp[mt][j] += __shfl_xor(mp[mt][j], 1);
                    mp[mt][j] += __shfl_xor(mp[mt][j], 2);
                    mp[mt][j] += __shfl_xor(mp[mt][j], 4);
                    mp[mt][j] += __shfl_xor(mp[mt][j], 8);
                }
            if (l15 == 0) {
                #pragma unroll
                for (int mt = 0; mt < 2; ++mt)
                    #pragma unroll
                    for (int j = 0; j < 4; ++j)
                        lds_mlp[pb][w][mt * 16 + l4 * 4 + j] = mp[mt][j];
            }
        }
        __syncthreads();   // sync3: mlp partials ready

        if (t < 32) {
            const int e = tile * 32 + t;
            if (e < E) {
                const float mlp = lds_mlp[pb][0][t] + lds_mlp[pb][1][t] + lds_mlp[pb][2][t]
                                + lds_mlp[pb][3][t] + b4_0;
                const float dot = lds_dot[pb][t];
                const float L0 = lds_g0[pb][t] + bg2_0, L1 = lds_g1[pb][t] + bg2_1;
                const float d = L1 - L0;
                const float z = __expf(-fabsf(d));
                const float inv = 1.f / (1.f + z);
                const float g1s = (d >= 0.f) ? inv : z * inv;
                out[e] = (1.f - g1s) * dot + g1s * mlp;
            }
        }
        // no sync4: parity buffers make the next iteration's writes hazard-free
        if (!hn) break;
        tile = ntile;
        pb ^= 1;
    }
#undef ISSUE
}

// ===================== FALLBACK (used only if ws too small) =====================
#define FB_ETILE 128
#define FB_WT1_OFF 0
#define FB_WT2_OFF 65536
#define FB_WT3_OFF 98304
#define FB_WTG1_OFF 106496
#define FB_WTOT 122880

__global__ void prep_weights_fb(const float* __restrict__ W1, const float* __restrict__ W2,
                                const float* __restrict__ W3, const float* __restrict__ Wg1,
                                unsigned short* __restrict__ ws) {
    int idx = blockIdx.x * 256 + threadIdx.x;
    if (idx >= FB_WTOT) return;
    float v;
    if (idx < FB_WT2_OFF)      { int n = idx >> 8, k = idx & 255; v = W1[k * 256 + n]; }
    else if (idx < FB_WT3_OFF) { int loc = idx - FB_WT2_OFF; int n = loc >> 8, k = loc & 255; v = W2[k * 128 + n]; }
    else if (idx < FB_WTG1_OFF){ int loc = idx - FB_WT3_OFF; int n = loc >> 7, k = loc & 127; v = W3[k * 64 + n]; }
    else                       { int loc = idx - FB_WTG1_OFF; int n = loc >> 8, k = loc & 255; v = Wg1[k * 64 + n]; }
    ws[idx] = f2bf_bits(v);
}

__global__ __launch_bounds__(512, 2)
void fused_edge_kernel_fb(const float* __restrict__ h_user, const float* __restrict__ h_item,
                          const int* __restrict__ src, const int* __restrict__ dst,
                          const unsigned short* __restrict__ wsmat,
                          const float* __restrict__ b1, const float* __restrict__ b2,
                          const float* __restrict__ b3, const float* __restrict__ b4,
                          const float* __restrict__ W4, const float* __restrict__ bg1,
                          const float* __restrict__ Wg2, const float* __restrict__ bg2,
                          float* __restrict__ out, int E) {
    __shared__ __align__(16) unsigned short lds_e[FB_ETILE * 256];
    __shared__ __align__(16) unsigned short lds_x1[FB_ETILE * 256];
    __shared__ float lds_dot[FB_ETILE];
    const unsigned short* wt1  = wsmat + FB_WT1_OFF;
    const unsigned short* wt2  = wsmat + FB_WT2_OFF;
    const unsigned short* wt3  = wsmat + FB_WT3_OFF;
    const unsigned short* wtg1 = wsmat + FB_WTG1_OFF;
    const int t = threadIdx.x, eb = blockIdx.x * FB_ETILE;
    const int w = t >> 6, l = t & 63, l15 = l & 15, l4 = l >> 4;
    {
        const int r = t >> 2, q = t & 3;
        int e = eb + r; if (e >= E) e = E - 1;
        const int idx = (q < 2) ? src[e] : dst[e];
        const float* rowp = ((q < 2) ? h_user : h_item) + (size_t)idx * 128 + (q & 1) * 64;
        const uint32_t cbase = (uint32_t)q * 64u;
        #pragma unroll
        for (int i = 0; i < 8; ++i) {
            f32x4 a = *reinterpret_cast<const f32x4*>(rowp + i * 8);
            f32x4 b = *reinterpret_cast<const f32x4*>(rowp + i * 8 + 4);
            bf16x8 p;
            #pragma unroll
            for (int j = 0; j < 4; ++j) { p[j] = (__bf16)a[j]; p[j + 4] = (__bf16)b[j]; }
            *reinterpret_cast<bf16x8*>((char*)lds_e + swz(r, cbase + i * 8u, 512)) = p;
        }
    }
    __syncthreads();
    {
        const int r = t >> 2, q = t & 3;
        float acc = 0.f;
        #pragma unroll
        for (int i = 0; i < 4; ++i) {
            uint32_t c = (uint32_t)q * 32u + i * 8u;
            bf16x8 sv = *reinterpret_cast<const bf16x8*>((const char*)lds_e + swz(r, c, 512));
            bf16x8 dv = *reinterpret_cast<const bf16x8*>((const char*)lds_e + swz(r, 128u + c, 512));
            #pragma unroll
            for (int j = 0; j < 8; ++j) acc += (float)sv[j] * (float)dv[j];
        }
        acc += __shfl_xor(acc, 1); acc += __shfl_xor(acc, 2);
        if (q == 0) lds_dot[r] = acc;
    }
    {
        const int mg = w >> 2, cg = w & 3;
        f32x4 acc[4][4] = {};
        #pragma unroll
        for (int kh = 0; kh < 2; ++kh) {
            bf16x8 afr[4][4];
            #pragma unroll
            for (int mt = 0; mt < 4; ++mt)
                #pragma unroll
                for (int kt = 0; kt < 4; ++kt)
                    afr[mt][kt] = *reinterpret_cast<const bf16x8*>((const char*)lds_e +
                        swz(mg * 64 + mt * 16 + l15, kh * 128 + kt * 32 + l4 * 8, 512));
            #pragma unroll
            for (int nt = 0; nt < 4; ++nt) {
                const int n = cg * 64 + nt * 16 + l15;
                #pragma unroll
                for (int kt = 0; kt < 4; ++kt) {
                    bf16x8 bfr = *reinterpret_cast<const bf16x8*>(wt1 + n * 256 + kh * 128 + kt * 32 + l4 * 8);
                    #pragma unroll
                    for (int mt = 0; mt < 4; ++mt)
                        acc[mt][nt] = __builtin_amdgcn_mfma_f32_16x16x32_bf16(afr[mt][kt], bfr, acc[mt][nt], 0, 0, 0);
                }
            }
        }
        #pragma unroll
        for (int nt = 0; nt < 4; ++nt) {
            const int col = cg * 64 + nt * 16 + l15;
            const float bias = b1[col];
            #pragma unroll
            for (int mt = 0; mt < 4; ++mt) {
                const int row0 = mg * 64 + mt * 16 + l4 * 4;
                #pragma unroll
                for (int j = 0; j < 4; ++j) {
                    float v = fmaxf(acc[mt][nt][j] + bias, 0.f);
                    *reinterpret_cast<unsigned short*>((char*)lds_x1 + swz(row0 + j, col, 512)) = f2bf_bits(v);
                }
            }
        }
    }
    float l0p[4] = {0, 0, 0, 0}, l1p[4] = {0, 0, 0, 0};
    {
        bf16x8 ag[8];
        #pragma unroll
        for (int kt = 0; kt < 8; ++kt)
            ag[kt] = *reinterpret_cast<const bf16x8*>((const char*)lds_e + swz(w * 16 + l15, kt * 32 + l4 * 8, 512));
        f32x4 accg[4] = {};
        #pragma unroll
        for (int nt = 0; nt < 4; ++nt) {
            const int n = nt * 16 + l15;
            #pragma unroll
            for (int kt = 0; kt < 8; ++kt) {
                bf16x8 bfr = *reinterpret_cast<const bf16x8*>(wtg1 + n * 256 + kt * 32 + l4 * 8);
                accg[nt] = __builtin_amdgcn_mfma_f32_16x16x32_bf16(ag[kt], bfr, accg[nt], 0, 0, 0);
            }
        }
        #pragma unroll
        for (int nt = 0; nt < 4; ++nt) {
            const int col = nt * 16 + l15;
            const float bg = bg1[col];
            const float w0 = Wg2[col * 2 + 0], w1 = Wg2[col * 2 + 1];
            #pragma unroll
            for (int j = 0; j < 4; ++j) {
                float v = fmaxf(accg[nt][j] + bg, 0.f);
                l0p[j] += v * w0; l1p[j] += v * w1;
            }
        }
        #pragma unroll
        for (int j = 0; j < 4; ++j)
            #pragma unroll
            for (int m = 1; m < 16; m <<= 1) {
                l0p[j] += __shfl_xor(l0p[j], m);
                l1p[j] += __shfl_xor(l1p[j], m);
            }
    }
    __syncthreads();
    {
        const int mg = w >> 1, cg = w & 1;
        bf16x8 a2[2][8];
        #pragma unroll
        for (int mt = 0; mt < 2; ++mt)
            #pragma unroll
            for (int kt = 0; kt < 8; ++kt)
                a2[mt][kt] = *reinterpret_cast<const bf16x8*>((const char*)lds_x1 +
                    swz(mg * 32 + mt * 16 + l15, kt * 32 + l4 * 8, 512));
        f32x4 acc2[2][4] = {};
        #pragma unroll
        for (int nt = 0; nt < 4; ++nt) {
            const int n = cg * 64 + nt * 16 + l15;
            #pragma unroll
            for (int kt = 0; kt < 8; ++kt) {
                bf16x8 bfr = *reinterpret_cast<const bf16x8*>(wt2 + n * 256 + kt * 32 + l4 * 8);
                #pragma unroll
                for (int mt = 0; mt < 2; ++mt)
                    acc2[mt][nt] = __builtin_amdgcn_mfma_f32_16x16x32_bf16(a2[mt][kt], bfr, acc2[mt][nt], 0, 0, 0);
            }
        }
        #pragma unroll
        for (int nt = 0; nt < 4; ++nt) {
            const int col = cg * 64 + nt * 16 + l15;
            const float bias = b2[col];
            #pragma unroll
            for (int mt = 0; mt < 2; ++mt) {
                const int row0 = mg * 32 + mt * 16 + l4 * 4;
                #pragma unroll
                for (int j = 0; j < 4; ++j) {
                    float v = fmaxf(acc2[mt][nt][j] + bias, 0.f);
                    *reinterpret_cast<unsigned short*>((char*)lds_e + swz(row0 + j, col, 256)) = f2bf_bits(v);
                }
            }
        }
    }
    __syncthreads();
    {
        float mlpp[4] = {0, 0, 0, 0};
        bf16x8 a3[4];
        #pragma unroll
        for (int kt = 0; kt < 4; ++kt)
            a3[kt] = *reinterpret_cast<const bf16x8*>((const char*)lds_e + swz(w * 16 + l15, kt * 32 + l4 * 8, 256));
        f32x4 acc3[4] = {};
        #pragma unroll
        for (int nt = 0; nt < 4; ++nt) {
            const int n = nt * 16 + l15;
            #pragma unroll
            for (int kt = 0; kt < 4; ++kt) {
                bf16x8 bfr = *reinterpret_cast<const bf16x8*>(wt3 + n * 128 + kt * 32 + l4 * 8);
                acc3[nt] = __builtin_amdgcn_mfma_f32_16x16x32_bf16(a3[kt], bfr, acc3[nt], 0, 0, 0);
            }
        }
        #pragma unroll
        for (int nt = 0; nt < 4; ++nt) {
            const int col = nt * 16 + l15;
            const float b3v = b3[col];
            const float w4v = W4[col];
            #pragma unroll
            for (int j = 0; j < 4; ++j) {
                float v = fmaxf(acc3[nt][j] + b3v, 0.f);
                mlpp[j] += v * w4v;
            }
        }
        #pragma unroll
        for (int j = 0; j < 4; ++j)
            #pragma unroll
            for (int m = 1; m < 16; m <<= 1)
                mlpp[j] += __shfl_xor(mlpp[j], m);
        if (l15 == 0) {
            #pragma unroll
            for (int j = 0; j < 4; ++j) {
                const int rr = w * 16 + l4 * 4 + j;
                const int e = eb + rr;
                if (e < E) {
                    const float dot = lds_dot[rr];
                    const float mlp = mlpp[j] + b4[0];
                    const float L0 = l0p[j] + bg2[0];
                    const float L1 = l1p[j] + bg2[1];
                    const float d = L1 - L0;
                    const float z = __expf(-fabsf(d));
                    const float inv = 1.f / (1.f + z);
                    const float g1 = (d >= 0.f) ? inv : z * inv;
                    out[e] = (1.f - g1) * dot + g1 * mlp;
                }
            }
        }
    }
}

// ===================== launch =====================
extern "C" void kernel_launch(void* const* d_in, const int* in_sizes, int n_in,
                              void* d_out, int out_size, void* d_ws, size_t ws_size,
                              hipStream_t stream) {
    const float* h_user = (const float*)d_in[0];
    const float* h_item = (const float*)d_in[1];
    const int*   src    = (const int*)d_in[2];
    const int*   dst    = (const int*)d_in[3];
    const float* W1  = (const float*)d_in[4];
    const float* b1  = (const float*)d_in[5];
    const float* W2  = (const float*)d_in[6];
    const float* b2  = (const float*)d_in[7];
    const float* W3  = (const float*)d_in[8];
    const float* b3  = (const float*)d_in[9];
    const float* W4  = (const float*)d_in[10];
    const float* b4  = (const float*)d_in[11];
    const float* Wg1 = (const float*)d_in[12];
    const float* bg1 = (const float*)d_in[13];
    const float* Wg2 = (const float*)d_in[14];
    const float* bg2 = (const float*)d_in[15];
    const int E  = in_sizes[2];
    const int nu = in_sizes[0] / 128;
    const int ni = in_sizes[1] / 128;

    unsigned short* ws = (unsigned short*)d_ws;
    char* wsb = (char*)d_ws;

    // fast-path table layout (byte offsets past the bf16 weight blob)
    size_t off = OFF_TBL_B;
    uint8_t* PU8 = (uint8_t*)(wsb + off); off += (size_t)nu * 256;
    uint8_t* PI8 = (uint8_t*)(wsb + off); off += (size_t)ni * 256;
    unsigned short* PGU  = (unsigned short*)(wsb + off); off += (size_t)nu * 128;
    unsigned short* PGI  = (unsigned short*)(wsb + off); off += (size_t)ni * 128;
    unsigned short* HU16 = (unsigned short*)(wsb + off); off += (size_t)nu * 256;
    unsigned short* HI16 = (unsigned short*)(wsb + off); off += (size_t)ni * 256;
    const size_t need_bytes = off;

    if (ws_size >= need_bytes) {
        prep_weights_fast<<<(PREP_TOT + 255) / 256, 256, 0, stream>>>(W1, Wg1, W2, W3, ws);
        const int nbu = (nu + 31) / 32, nbi = (ni + 31) / 32;
        proj_kernel<<<nbu + nbi, 256, 0, stream>>>(h_user, h_item, ws, b1, bg1,
                                                   PU8, PI8, PGU, PGI, HU16, HI16, nu, ni, nbu);
        edge_main<<<GRID_MAIN, 256, 0, stream>>>(src, dst, PU8, PI8, PGU, PGI, HU16, HI16,
                                                 ws + OFF_W2T_E, ws + OFF_W3T_E,
                                                 b2, b3, b4, W4, Wg2, bg2, (float*)d_out, E);
    } else {
        prep_weights_fb<<<(FB_WTOT + 255) / 256, 256, 0, stream>>>(W1, W2, W3, Wg1, ws);
        const int nblk = (E + FB_ETILE - 1) / FB_ETILE;
        fused_edge_kernel_fb<<<nblk, 512, 0, stream>>>(h_user, h_item, src, dst, ws,
                                                       b1, b2, b3, b4, W4, bg1, Wg2, bg2,
                                                       (float*)d_out, E);
    }
}

// Round 16
// 194.029 us; speedup vs baseline: 1.2914x; 1.0224x over previous
//
#include <hip/hip_runtime.h>
#include <hip/hip_bf16.h>
#include <stdint.h>

typedef __bf16 bf16x8 __attribute__((ext_vector_type(8)));
typedef float f32x4 __attribute__((ext_vector_type(4)));
typedef float f32x2 __attribute__((ext_vector_type(2)));
typedef uint32_t u32x4 __attribute__((ext_vector_type(4)));

// LDS XOR swizzle (Guideline 4): spreads 8 rows across distinct 16B slots.
__device__ __forceinline__ uint32_t swz(uint32_t row, uint32_t col, uint32_t strideB) {
    return (row * strideB + col * 2u) ^ ((row & 7u) << 4);
}
__device__ __forceinline__ unsigned short f2bf_bits(float v) {
    __bf16 h = (__bf16)v; return __builtin_bit_cast(unsigned short, h);
}
__device__ __forceinline__ float bf2f(__bf16 h) { return (float)h; }

// ===================== FAST PATH =====================
// ws element offsets (ushort) for weight blobs
#define OFF_BU_E    0         // [320][128]  (W1u | Wg1u)^T
#define OFF_BI_E    40960     // [320][128]  (W1i | Wg1i)^T
#define OFF_W2T_E   81920     // [128][256]  W2^T
#define OFF_W3T_E   114688    // [64][128]   W3^T
#define PREP_TOT    122880
#define OFF_TBL_B   262144    // tables start (byte offset)

// Per-node interleaved record (round-16): one 640B contiguous blob per node
//   [  0..255]  P   fp8 e4m3 (256 cols)
//   [256..383]  PG  bf16     (64 cols)
//   [384..639]  H16 bf16     (128 cols)
// One DRAM-row/L3 locality per node instead of 3 disjoint tables; per-edge
// gather touches 2 regions instead of 6.
#define REC_B 640

__global__ void prep_weights_fast(const float* __restrict__ W1, const float* __restrict__ Wg1,
                                  const float* __restrict__ W2, const float* __restrict__ W3,
                                  unsigned short* __restrict__ ws) {
    int idx = blockIdx.x * 256 + threadIdx.x;
    if (idx >= PREP_TOT) return;
    float v;
    if (idx < OFF_BI_E) {                       // Bu[n][k] = W1[k][n] or Wg1[k][n-256], k user rows
        int n = idx >> 7, k = idx & 127;
        v = (n < 256) ? W1[k * 256 + n] : Wg1[k * 64 + (n - 256)];
    } else if (idx < OFF_W2T_E) {               // Bi: item rows k+128
        int loc = idx - OFF_BI_E; int n = loc >> 7, k = loc & 127;
        v = (n < 256) ? W1[(128 + k) * 256 + n] : Wg1[(128 + k) * 64 + (n - 256)];
    } else if (idx < OFF_W3T_E) {               // W2T [128n][256k]
        int loc = idx - OFF_W2T_E; int n = loc >> 8, k = loc & 255;
        v = W2[k * 128 + n];
    } else {                                    // W3T [64n][128k]
        int loc = idx - OFF_W3T_E; int n = loc >> 7, k = loc & 127;
        v = W3[k * 64 + n];
    }
    ws[idx] = f2bf_bits(v);
}

// Merged dense projection (user blocks then item blocks):
// [P | Pg](+bias for user) = H @ Bmat^T; also emits bf16 copy of H.
// P stored as fp8 e4m3 (MLP trunk tolerates ~6% rel err; dot/gate paths stay bf16).
// 32-row / 256-thread blocks = measured optimum (round-12: ~56us); round-13
// lesson: smaller blocks are drain-bound. Output goes to the interleaved REC.
#define POUT_STRIDE 328
__global__ __launch_bounds__(256, 2)
void proj_kernel(const float* __restrict__ HU, const float* __restrict__ HI,
                 const unsigned short* __restrict__ wsmat,
                 const float* __restrict__ b1, const float* __restrict__ bg1,
                 uint8_t* __restrict__ RECU, uint8_t* __restrict__ RECI,
                 int nu, int ni, int nbu) {
    // aliased: phase A = bf16 input tile [32][128] swz256 (8KB); phase B = out [32][328] (21KB)
    __shared__ __align__(16) unsigned short lds[32 * POUT_STRIDE];
    const int t = threadIdx.x, w = t >> 6, l = t & 63, l15 = l & 15, l4 = l >> 4;
    const bool isU = (int)blockIdx.x < nbu;
    const int rb = (isU ? (int)blockIdx.x : (int)blockIdx.x - nbu) * 32;
    const int rows = isU ? nu : ni;
    const float* H = isU ? HU : HI;
    const unsigned short* Bmat = wsmat + (isU ? OFF_BU_E : OFF_BI_E);
    uint8_t* REC = isU ? RECU : RECI;
    const int addBias = isU ? 1 : 0;

    {
        const int r = t >> 3, q = t & 7;   // 8 threads/row, 16 floats each
        int rg = rb + r; int rc = rg < rows ? rg : rows - 1;
        const float* p = H + (size_t)rc * 128 + q * 16;
        f32x4 f0 = *(const f32x4*)(p);     f32x4 f1 = *(const f32x4*)(p + 4);
        f32x4 f2 = *(const f32x4*)(p + 8); f32x4 f3 = *(const f32x4*)(p + 12);
        bf16x8 h0, h1;
        #pragma unroll
        for (int j = 0; j < 4; ++j) {
            h0[j] = (__bf16)f0[j]; h0[j + 4] = (__bf16)f1[j];
            h1[j] = (__bf16)f2[j]; h1[j + 4] = (__bf16)f3[j];
        }
        *(bf16x8*)((char*)lds + swz(r, q * 16, 256)) = h0;
        *(bf16x8*)((char*)lds + swz(r, q * 16 + 8, 256)) = h1;
        if (rg < rows) {
            uint8_t* hrec = REC + (size_t)rg * REC_B + 384 + q * 32;
            *(bf16x8*)(hrec)      = h0;
            *(bf16x8*)(hrec + 16) = h1;
        }
    }
    __syncthreads();
    // GEMM: M=32, K=128, N=320. Wave w -> cols w*80..+79 (5 n-tiles), rows 0..31 (2 m-tiles)
    f32x4 acc[2][5] = {};
    #pragma unroll
    for (int kt = 0; kt < 4; ++kt) {
        bf16x8 aA = *(const bf16x8*)((const char*)lds + swz(l15, kt * 32 + l4 * 8, 256));
        bf16x8 aB = *(const bf16x8*)((const char*)lds + swz(16 + l15, kt * 32 + l4 * 8, 256));
        #pragma unroll
        for (int nt = 0; nt < 5; ++nt) {
            const int n = w * 80 + nt * 16 + l15;
            bf16x8 bfr = *(const bf16x8*)(Bmat + n * 128 + kt * 32 + l4 * 8);
            acc[0][nt] = __builtin_amdgcn_mfma_f32_16x16x32_bf16(aA, bfr, acc[0][nt], 0, 0, 0);
            acc[1][nt] = __builtin_amdgcn_mfma_f32_16x16x32_bf16(aB, bfr, acc[1][nt], 0, 0, 0);
        }
    }
    __syncthreads();   // input-tile reads done; reuse lds as output stage
    #pragma unroll
    for (int nt = 0; nt < 5; ++nt) {
        const int n = w * 80 + nt * 16 + l15;
        const float bias = addBias ? ((n < 256) ? b1[n] : bg1[n - 256]) : 0.f;
        #pragma unroll
        for (int mt = 0; mt < 2; ++mt) {
            #pragma unroll
            for (int j = 0; j < 4; ++j) {
                const int row = mt * 16 + l4 * 4 + j;
                lds[row * POUT_STRIDE + n] = f2bf_bits(acc[mt][nt][j] + bias);  // NO relu here
            }
        }
    }
    __syncthreads();
    {
        const int r = t >> 3, q = t & 7;
        const int rg = rb + r;
        if (rg < rows) {
            uint8_t* rec = REC + (size_t)rg * REC_B;
            uint32_t dw[8];
            #pragma unroll
            for (int vb = 0; vb < 4; ++vb) {
                bf16x8 pv = *(const bf16x8*)(&lds[r * POUT_STRIDE + q * 32 + vb * 8]);
                float f[8];
                #pragma unroll
                for (int j = 0; j < 8; ++j) f[j] = bf2f(pv[j]);
                uint32_t d0 = 0, d1 = 0;
                d0 = __builtin_amdgcn_cvt_pk_fp8_f32(f[0], f[1], d0, false);
                d0 = __builtin_amdgcn_cvt_pk_fp8_f32(f[2], f[3], d0, true);
                d1 = __builtin_amdgcn_cvt_pk_fp8_f32(f[4], f[5], d1, false);
                d1 = __builtin_amdgcn_cvt_pk_fp8_f32(f[6], f[7], d1, true);
                dw[vb * 2] = d0; dw[vb * 2 + 1] = d1;
            }
            u32x4 s0 = {dw[0], dw[1], dw[2], dw[3]};
            u32x4 s1 = {dw[4], dw[5], dw[6], dw[7]};
            *(u32x4*)(rec + q * 32)      = s0;
            *(u32x4*)(rec + q * 32 + 16) = s1;
            bf16x8 gv = *(const bf16x8*)(&lds[r * POUT_STRIDE + 256 + q * 8]);
            *(bf16x8*)(rec + 256 + q * 16) = gv;
        }
    }
}

#define GRID_MAIN 512   // exactly co-resident (2 blocks/CU x 256 CU): one persistent
                        // generation, continuous prefetch chain (round-15: -8us).

// Persistent main kernel, 256 threads / 4 waves, ETILE=32 — round-11/12 structure.
// 3 barriers/iter; parity double-buffer removes sync4. Round-9: no asm barriers.
// Round-10: keep phase3 spread over all 4 waves. Round-16: interleaved REC gather.
__global__ __launch_bounds__(256, 2)
void edge_main(const int* __restrict__ src, const int* __restrict__ dst,
               const uint8_t* __restrict__ RECU, const uint8_t* __restrict__ RECI,
               const unsigned short* __restrict__ W2T, const unsigned short* __restrict__ W3T,
               const float* __restrict__ b2, const float* __restrict__ b3,
               const float* __restrict__ b4, const float* __restrict__ W4,
               const float* __restrict__ Wg2, const float* __restrict__ bg2,
               float* __restrict__ out, int E) {
    __shared__ __align__(16) unsigned short lds_x1[32 * 256];  // 16KB, swz 512
    __shared__ __align__(16) unsigned short lds_x2[32 * 128];  // 8KB, swz 256
    __shared__ float lds_dot[2][32], lds_g0[2][32], lds_g1[2][32];  // parity dbuf
    __shared__ float lds_mlp[2][4][32];
    __shared__ float lds_wg0[64], lds_wg1[64];                 // Wg2 columns (512B)

    const int t = threadIdx.x, w = t >> 6, l = t & 63, l15 = l & 15, l4 = l >> 4;
    const int r = t >> 3, q = t & 7;        // gather roles: edge slot r (0..31), chunk q

    // per-wave column bases: x2 -> cols w*32..+31 ; x3 -> cols w*16..+15
    const unsigned short* w2p = W2T + (w * 32 + l15) * 256 + l4 * 8;   // nt=1 adds 16*256
    const unsigned short* w3p = W3T + (w * 16 + l15) * 128 + l4 * 8;
    float b2v[2];
    #pragma unroll
    for (int nt = 0; nt < 2; ++nt) b2v[nt] = b2[w * 32 + nt * 16 + l15];
    const float b3v = b3[w * 16 + l15], w4v = W4[w * 16 + l15];
    const float bg2_0 = bg2[0], bg2_1 = bg2[1], b4_0 = b4[0];

    if (t < 64) { lds_wg0[t] = Wg2[t * 2]; lds_wg1[t] = Wg2[t * 2 + 1]; }

    const int NT = (E + 31) >> 5;
    int tile = blockIdx.x;
    if (tile >= NT) return;

    u32x4 gpu8[2], gpi8[2];
    bf16x8 ghu[2], ghi[2], gpg_u, gpg_i;
#define ISSUE(TT) do { \
        int e_ = (TT) * 32 + r; if (e_ >= E) e_ = E - 1; \
        const uint8_t* bu_ = RECU + (size_t)src[e_] * REC_B; \
        const uint8_t* bi_ = RECI + (size_t)dst[e_] * REC_B; \
        gpu8[0] = *(const u32x4*)(bu_ + q * 32);       gpu8[1] = *(const u32x4*)(bu_ + q * 32 + 16); \
        gpi8[0] = *(const u32x4*)(bi_ + q * 32);       gpi8[1] = *(const u32x4*)(bi_ + q * 32 + 16); \
        gpg_u   = *(const bf16x8*)(bu_ + 256 + q * 16); \
        gpg_i   = *(const bf16x8*)(bi_ + 256 + q * 16); \
        ghu[0] = *(const bf16x8*)(bu_ + 384 + q * 32); ghu[1] = *(const bf16x8*)(bu_ + 384 + q * 32 + 16); \
        ghi[0] = *(const bf16x8*)(bi_ + 384 + q * 32); ghi[1] = *(const bf16x8*)(bi_ + 384 + q * 32 + 16); \
    } while (0)

    ISSUE(tile);
    __syncthreads();   // prologue: lds_wg ready

    int pb = 0;
    for (;;) {
        // ---- phase 1: x1 = relu(fp8(P_u)+fp8(P_i)) -> LDS bf16; dot; gates -> [pb]
        #pragma unroll
        for (int v = 0; v < 2; ++v) {
            #pragma unroll
            for (int h = 0; h < 2; ++h) {
                bf16x8 o;
                #pragma unroll
                for (int d = 0; d < 2; ++d) {
                    const uint32_t du = gpu8[v][2 * h + d], di = gpi8[v][2 * h + d];
                    f32x2 a0 = __builtin_amdgcn_cvt_pk_f32_fp8(du, false);
                    f32x2 a1 = __builtin_amdgcn_cvt_pk_f32_fp8(du, true);
                    f32x2 c0 = __builtin_amdgcn_cvt_pk_f32_fp8(di, false);
                    f32x2 c1 = __builtin_amdgcn_cvt_pk_f32_fp8(di, true);
                    o[d * 4 + 0] = (__bf16)fmaxf(a0[0] + c0[0], 0.f);
                    o[d * 4 + 1] = (__bf16)fmaxf(a0[1] + c0[1], 0.f);
                    o[d * 4 + 2] = (__bf16)fmaxf(a1[0] + c1[0], 0.f);
                    o[d * 4 + 3] = (__bf16)fmaxf(a1[1] + c1[1], 0.f);
                }
                *(bf16x8*)((char*)lds_x1 + swz(r, q * 32 + v * 16 + h * 8, 512)) = o;
            }
        }
        {
            float dacc = 0.f;
            #pragma unroll
            for (int v = 0; v < 2; ++v)
                #pragma unroll
                for (int j = 0; j < 8; ++j)
                    dacc += bf2f(ghu[v][j]) * bf2f(ghi[v][j]);
            dacc += __shfl_xor(dacc, 1); dacc += __shfl_xor(dacc, 2); dacc += __shfl_xor(dacc, 4);
            f32x4 wg0a = *(const f32x4*)(&lds_wg0[q * 8]);
            f32x4 wg0b = *(const f32x4*)(&lds_wg0[q * 8 + 4]);
            f32x4 wg1a = *(const f32x4*)(&lds_wg1[q * 8]);
            f32x4 wg1b = *(const f32x4*)(&lds_wg1[q * 8 + 4]);
            float g0 = 0.f, g1 = 0.f;
            #pragma unroll
            for (int i = 0; i < 4; ++i) {
                float va = fmaxf(bf2f(gpg_u[i]) + bf2f(gpg_i[i]), 0.f);
                float vb = fmaxf(bf2f(gpg_u[i + 4]) + bf2f(gpg_i[i + 4]), 0.f);
                g0 += va * wg0a[i] + vb * wg0b[i];
                g1 += va * wg1a[i] + vb * wg1b[i];
            }
            g0 += __shfl_xor(g0, 1); g0 += __shfl_xor(g0, 2); g0 += __shfl_xor(g0, 4);
            g1 += __shfl_xor(g1, 1); g1 += __shfl_xor(g1, 2); g1 += __shfl_xor(g1, 4);
            if (q == 0) { lds_dot[pb][r] = dacc; lds_g0[pb][r] = g0; lds_g1[pb][r] = g1; }
        }
        __syncthreads();   // sync1: x1/dot/gates visible

        const int ntile = tile + GRID_MAIN;
        const bool hn = ntile < NT;
        if (hn) ISSUE(ntile);   // T14 prefetch; drains at sync2 (cover = phase 2)

        // ---- phase 2: x2 = relu(x1 @ W2 + b2): 32 rows, wave w -> cols w*32..+31
        {
            f32x4 acc2[2][2] = {};
            #pragma unroll
            for (int kt = 0; kt < 8; ++kt) {
                bf16x8 aA = *(const bf16x8*)((const char*)lds_x1 + swz(l15, kt * 32 + l4 * 8, 512));
                bf16x8 aB = *(const bf16x8*)((const char*)lds_x1 + swz(16 + l15, kt * 32 + l4 * 8, 512));
                bf16x8 bf0 = *(const bf16x8*)(w2p + kt * 32);
                bf16x8 bf1 = *(const bf16x8*)(w2p + 16 * 256 + kt * 32);
                acc2[0][0] = __builtin_amdgcn_mfma_f32_16x16x32_bf16(aA, bf0, acc2[0][0], 0, 0, 0);
                acc2[1][0] = __builtin_amdgcn_mfma_f32_16x16x32_bf16(aB, bf0, acc2[1][0], 0, 0, 0);
                acc2[0][1] = __builtin_amdgcn_mfma_f32_16x16x32_bf16(aA, bf1, acc2[0][1], 0, 0, 0);
                acc2[1][1] = __builtin_amdgcn_mfma_f32_16x16x32_bf16(aB, bf1, acc2[1][1], 0, 0, 0);
            }
            #pragma unroll
            for (int mt = 0; mt < 2; ++mt)
                #pragma unroll
                for (int nt = 0; nt < 2; ++nt) {
                    const int col = w * 32 + nt * 16 + l15;
                    #pragma unroll
                    for (int j = 0; j < 4; ++j) {
                        const int row = mt * 16 + l4 * 4 + j;
                        float v = fmaxf(acc2[mt][nt][j] + b2v[nt], 0.f);
                        *(unsigned short*)((char*)lds_x2 + swz(row, col, 256)) = f2bf_bits(v);
                    }
                }
        }
        __syncthreads();   // sync2: x2 ready; x1 free

        // ---- phase 3: x3 = relu(x2 @ W3 + b3), fused W4 head: wave w -> cols w*16..+15
        {
            f32x4 acc3[2] = {};
            #pragma unroll
            for (int kt = 0; kt < 4; ++kt) {
                bf16x8 a0 = *(const bf16x8*)((const char*)lds_x2 + swz(l15, kt * 32 + l4 * 8, 256));
                bf16x8 a1 = *(const bf16x8*)((const char*)lds_x2 + swz(16 + l15, kt * 32 + l4 * 8, 256));
                bf16x8 bfr = *(const bf16x8*)(w3p + kt * 32);
                acc3[0] = __builtin_amdgcn_mfma_f32_16x16x32_bf16(a0, bfr, acc3[0], 0, 0, 0);
                acc3[1] = __builtin_amdgcn_mfma_f32_16x16x32_bf16(a1, bfr, acc3[1], 0, 0, 0);
            }
            float mp[2][4];
            #pragma unroll
            for (int mt = 0; mt < 2; ++mt)
                #pragma unroll
                for (int j = 0; j < 4; ++j) {
                    mp[mt][j] = fmaxf(acc3[mt][j] + b3v, 0.f) * w4v;
                    mp[mt][j] += __shfl_xor(mp[mt][j], 1);
                    mp[mt][j] += __shfl_xor(mp[mt][j], 2);
                    mp[mt][j] += __shfl_xor(mp[mt][j], 4);
                    mp[mt][j] += __shfl_xor(mp[mt][j], 8);
                }
            if (l15 == 0) {
                #pragma unroll
                for (int mt = 0; mt < 2; ++mt)
                    #pragma unroll
                    for (int j = 0; j < 4; ++j)
                        lds_mlp[pb][w][mt * 16 + l4 * 4 + j] = mp[mt][j];
            }
        }
        __syncthreads();   // sync3: mlp partials ready

        if (t < 32) {
            const int e = tile * 32 + t;
            if (e < E) {
                const float mlp = lds_mlp[pb][0][t] + lds_mlp[pb][1][t] + lds_mlp[pb][2][t]
                                + lds_mlp[pb][3][t] + b4_0;
                const float dot = lds_dot[pb][t];
                const float L0 = lds_g0[pb][t] + bg2_0, L1 = lds_g1[pb][t] + bg2_1;
                const float d = L1 - L0;
                const float z = __expf(-fabsf(d));
                const float inv = 1.f / (1.f + z);
                const float g1s = (d >= 0.f) ? inv : z * inv;
                out[e] = (1.f - g1s) * dot + g1s * mlp;
            }
        }
        // no sync4: parity buffers make the next iteration's writes hazard-free
        if (!hn) break;
        tile = ntile;
        pb ^= 1;
    }
#undef ISSUE
}

// ===================== FALLBACK (used only if ws too small) =====================
#define FB_ETILE 128
#define FB_WT1_OFF 0
#define FB_WT2_OFF 65536
#define FB_WT3_OFF 98304
#define FB_WTG1_OFF 106496
#define FB_WTOT 122880

__global__ void prep_weights_fb(const float* __restrict__ W1, const float* __restrict__ W2,
                                const float* __restrict__ W3, const float* __restrict__ Wg1,
                                unsigned short* __restrict__ ws) {
    int idx = blockIdx.x * 256 + threadIdx.x;
    if (idx >= FB_WTOT) return;
    float v;
    if (idx < FB_WT2_OFF)      { int n = idx >> 8, k = idx & 255; v = W1[k * 256 + n]; }
    else if (idx < FB_WT3_OFF) { int loc = idx - FB_WT2_OFF; int n = loc >> 8, k = loc & 255; v = W2[k * 128 + n]; }
    else if (idx < FB_WTG1_OFF){ int loc = idx - FB_WT3_OFF; int n = loc >> 7, k = loc & 127; v = W3[k * 64 + n]; }
    else                       { int loc = idx - FB_WTG1_OFF; int n = loc >> 8, k = loc & 255; v = Wg1[k * 64 + n]; }
    ws[idx] = f2bf_bits(v);
}

__global__ __launch_bounds__(512, 2)
void fused_edge_kernel_fb(const float* __restrict__ h_user, const float* __restrict__ h_item,
                          const int* __restrict__ src, const int* __restrict__ dst,
                          const unsigned short* __restrict__ wsmat,
                          const float* __restrict__ b1, const float* __restrict__ b2,
                          const float* __restrict__ b3, const float* __restrict__ b4,
                          const float* __restrict__ W4, const float* __restrict__ bg1,
                          const float* __restrict__ Wg2, const float* __restrict__ bg2,
                          float* __restrict__ out, int E) {
    __shared__ __align__(16) unsigned short lds_e[FB_ETILE * 256];
    __shared__ __align__(16) unsigned short lds_x1[FB_ETILE * 256];
    __shared__ float lds_dot[FB_ETILE];
    const unsigned short* wt1  = wsmat + FB_WT1_OFF;
    const unsigned short* wt2  = wsmat + FB_WT2_OFF;
    const unsigned short* wt3  = wsmat + FB_WT3_OFF;
    const unsigned short* wtg1 = wsmat + FB_WTG1_OFF;
    const int t = threadIdx.x, eb = blockIdx.x * FB_ETILE;
    const int w = t >> 6, l = t & 63, l15 = l & 15, l4 = l >> 4;
    {
        const int r = t >> 2, q = t & 3;
        int e = eb + r; if (e >= E) e = E - 1;
        const int idx = (q < 2) ? src[e] : dst[e];
        const float* rowp = ((q < 2) ? h_user : h_item) + (size_t)idx * 128 + (q & 1) * 64;
        const uint32_t cbase = (uint32_t)q * 64u;
        #pragma unroll
        for (int i = 0; i < 8; ++i) {
            f32x4 a = *reinterpret_cast<const f32x4*>(rowp + i * 8);
            f32x4 b = *reinterpret_cast<const f32x4*>(rowp + i * 8 + 4);
            bf16x8 p;
            #pragma unroll
            for (int j = 0; j < 4; ++j) { p[j] = (__bf16)a[j]; p[j + 4] = (__bf16)b[j]; }
            *reinterpret_cast<bf16x8*>((char*)lds_e + swz(r, cbase + i * 8u, 512)) = p;
        }
    }
    __syncthreads();
    {
        const int r = t >> 2, q = t & 3;
        float acc = 0.f;
        #pragma unroll
        for (int i = 0; i < 4; ++i) {
            uint32_t c = (uint32_t)q * 32u + i * 8u;
            bf16x8 sv = *reinterpret_cast<const bf16x8*>((const char*)lds_e + swz(r, c, 512));
            bf16x8 dv = *reinterpret_cast<const bf16x8*>((const char*)lds_e + swz(r, 128u + c, 512));
            #pragma unroll
            for (int j = 0; j < 8; ++j) acc += (float)sv[j] * (float)dv[j];
        }
        acc += __shfl_xor(acc, 1); acc += __shfl_xor(acc, 2);
        if (q == 0) lds_dot[r] = acc;
    }
    {
        const int mg = w >> 2, cg = w & 3;
        f32x4 acc[4][4] = {};
        #pragma unroll
        for (int kh = 0; kh < 2; ++kh) {
            bf16x8 afr[4][4];
            #pragma unroll
            for (int mt = 0; mt < 4; ++mt)
                #pragma unroll
                for (int kt = 0; kt < 4; ++kt)
                    afr[mt][kt] = *reinterpret_cast<const bf16x8*>((const char*)lds_e +
                        swz(mg * 64 + mt * 16 + l15, kh * 128 + kt * 32 + l4 * 8, 512));
            #pragma unroll
            for (int nt = 0; nt < 4; ++nt) {
                const int n = cg * 64 + nt * 16 + l15;
                #pragma unroll
                for (int kt = 0; kt < 4; ++kt) {
                    bf16x8 bfr = *reinterpret_cast<const bf16x8*>(wt1 + n * 256 + kh * 128 + kt * 32 + l4 * 8);
                    #pragma unroll
                    for (int mt = 0; mt < 4; ++mt)
                        acc[mt][nt] = __builtin_amdgcn_mfma_f32_16x16x32_bf16(afr[mt][kt], bfr, acc[mt][nt], 0, 0, 0);
                }
            }
        }
        #pragma unroll
        for (int nt = 0; nt < 4; ++nt) {
            const int col = cg * 64 + nt * 16 + l15;
            const float bias = b1[col];
            #pragma unroll
            for (int mt = 0; mt < 4; ++mt) {
                const int row0 = mg * 64 + mt * 16 + l4 * 4;
                #pragma unroll
                for (int j = 0; j < 4; ++j) {
                    float v = fmaxf(acc[mt][nt][j] + bias, 0.f);
                    *reinterpret_cast<unsigned short*>((char*)lds_x1 + swz(row0 + j, col, 512)) = f2bf_bits(v);
                }
            }
        }
    }
    float l0p[4] = {0, 0, 0, 0}, l1p[4] = {0, 0, 0, 0};
    {
        bf16x8 ag[8];
        #pragma unroll
        for (int kt = 0; kt < 8; ++kt)
            ag[kt] = *reinterpret_cast<const bf16x8*>((const char*)lds_e + swz(w * 16 + l15, kt * 32 + l4 * 8, 512));
        f32x4 accg[4] = {};
        #pragma unroll
        for (int nt = 0; nt < 4; ++nt) {
            const int n = nt * 16 + l15;
            #pragma unroll
            for (int kt = 0; kt < 8; ++kt) {
                bf16x8 bfr = *reinterpret_cast<const bf16x8*>(wtg1 + n * 256 + kt * 32 + l4 * 8);
                accg[nt] = __builtin_amdgcn_mfma_f32_16x16x32_bf16(ag[kt], bfr, accg[nt], 0, 0, 0);
            }
        }
        #pragma unroll
        for (int nt = 0; nt < 4; ++nt) {
            const int col = nt * 16 + l15;
            const float bg = bg1[col];
            const float w0 = Wg2[col * 2 + 0], w1 = Wg2[col * 2 + 1];
            #pragma unroll
            for (int j = 0; j < 4; ++j) {
                float v = fmaxf(accg[nt][j] + bg, 0.f);
                l0p[j] += v * w0; l1p[j] += v * w1;
            }
        }
        #pragma unroll
        for (int j = 0; j < 4; ++j)
            #pragma unroll
            for (int m = 1; m < 16; m <<= 1) {
                l0p[j] += __shfl_xor(l0p[j], m);
                l1p[j] += __shfl_xor(l1p[j], m);
            }
    }
    __syncthreads();
    {
        const int mg = w >> 1, cg = w & 1;
        bf16x8 a2[2][8];
        #pragma unroll
        for (int mt = 0; mt < 2; ++mt)
            #pragma unroll
            for (int kt = 0; kt < 8; ++kt)
                a2[mt][kt] = *reinterpret_cast<const bf16x8*>((const char*)lds_x1 +
                    swz(mg * 32 + mt * 16 + l15, kt * 32 + l4 * 8, 512));
        f32x4 acc2[2][4] = {};
        #pragma unroll
        for (int nt = 0; nt < 4; ++nt) {
            const int n = cg * 64 + nt * 16 + l15;
            #pragma unroll
            for (int kt = 0; kt < 8; ++kt) {
                bf16x8 bfr = *reinterpret_cast<const bf16x8*>(wt2 + n * 256 + kt * 32 + l4 * 8);
                #pragma unroll
                for (int mt = 0; mt < 2; ++mt)
                    acc2[mt][nt] = __builtin_amdgcn_mfma_f32_16x16x32_bf16(a2[mt][kt], bfr, acc2[mt][nt], 0, 0, 0);
            }
        }
        #pragma unroll
        for (int nt = 0; nt < 4; ++nt) {
            const int col = cg * 64 + nt * 16 + l15;
            const float bias = b2[col];
            #pragma unroll
            for (int mt = 0; mt < 2; ++mt) {
                const int row0 = mg * 32 + mt * 16 + l4 * 4;
                #pragma unroll
                for (int j = 0; j < 4; ++j) {
                    float v = fmaxf(acc2[mt][nt][j] + bias, 0.f);
                    *reinterpret_cast<unsigned short*>((char*)lds_e + swz(row0 + j, col, 256)) = f2bf_bits(v);
                }
            }
        }
    }
    __syncthreads();
    {
        float mlpp[4] = {0, 0, 0, 0};
        bf16x8 a3[4];
        #pragma unroll
        for (int kt = 0; kt < 4; ++kt)
            a3[kt] = *reinterpret_cast<const bf16x8*>((const char*)lds_e + swz(w * 16 + l15, kt * 32 + l4 * 8, 256));
        f32x4 acc3[4] = {};
        #pragma unroll
        for (int nt = 0; nt < 4; ++nt) {
            const int n = nt * 16 + l15;
            #pragma unroll
            for (int kt = 0; kt < 4; ++kt) {
                bf16x8 bfr = *reinterpret_cast<const bf16x8*>(wt3 + n * 128 + kt * 32 + l4 * 8);
                acc3[nt] = __builtin_amdgcn_mfma_f32_16x16x32_bf16(a3[kt], bfr, acc3[nt], 0, 0, 0);
            }
        }
        #pragma unroll
        for (int nt = 0; nt < 4; ++nt) {
            const int col = nt * 16 + l15;
            const float b3v = b3[col];
            const float w4v = W4[col];
            #pragma unroll
            for (int j = 0; j < 4; ++j) {
                float v = fmaxf(acc3[nt][j] + b3v, 0.f);
                mlpp[j] += v * w4v;
            }
        }
        #pragma unroll
        for (int j = 0; j < 4; ++j)
            #pragma unroll
            for (int m = 1; m < 16; m <<= 1)
                mlpp[j] += __shfl_xor(mlpp[j], m);
        if (l15 == 0) {
            #pragma unroll
            for (int j = 0; j < 4; ++j) {
                const int rr = w * 16 + l4 * 4 + j;
                const int e = eb + rr;
                if (e < E) {
                    const float dot = lds_dot[rr];
                    const float mlp = mlpp[j] + b4[0];
                    const float L0 = l0p[j] + bg2[0];
                    const float L1 = l1p[j] + bg2[1];
                    const float d = L1 - L0;
                    const float z = __expf(-fabsf(d));
                    const float inv = 1.f / (1.f + z);
                    const float g1 = (d >= 0.f) ? inv : z * inv;
                    out[e] = (1.f - g1) * dot + g1 * mlp;
                }
            }
        }
    }
}

// ===================== launch =====================
extern "C" void kernel_launch(void* const* d_in, const int* in_sizes, int n_in,
                              void* d_out, int out_size, void* d_ws, size_t ws_size,
                              hipStream_t stream) {
    const float* h_user = (const float*)d_in[0];
    const float* h_item = (const float*)d_in[1];
    const int*   src    = (const int*)d_in[2];
    const int*   dst    = (const int*)d_in[3];
    const float* W1  = (const float*)d_in[4];
    const float* b1  = (const float*)d_in[5];
    const float* W2  = (const float*)d_in[6];
    const float* b2  = (const float*)d_in[7];
    const float* W3  = (const float*)d_in[8];
    const float* b3  = (const float*)d_in[9];
    const float* W4  = (const float*)d_in[10];
    const float* b4  = (const float*)d_in[11];
    const float* Wg1 = (const float*)d_in[12];
    const float* bg1 = (const float*)d_in[13];
    const float* Wg2 = (const float*)d_in[14];
    const float* bg2 = (const float*)d_in[15];
    const int E  = in_sizes[2];
    const int nu = in_sizes[0] / 128;
    const int ni = in_sizes[1] / 128;

    unsigned short* ws = (unsigned short*)d_ws;
    char* wsb = (char*)d_ws;

    // fast-path table layout (byte offsets past the bf16 weight blob)
    size_t off = OFF_TBL_B;
    uint8_t* RECU = (uint8_t*)(wsb + off); off += (size_t)nu * REC_B;
    uint8_t* RECI = (uint8_t*)(wsb + off); off += (size_t)ni * REC_B;
    const size_t need_bytes = off;

    if (ws_size >= need_bytes) {
        prep_weights_fast<<<(PREP_TOT + 255) / 256, 256, 0, stream>>>(W1, Wg1, W2, W3, ws);
        const int nbu = (nu + 31) / 32, nbi = (ni + 31) / 32;
        proj_kernel<<<nbu + nbi, 256, 0, stream>>>(h_user, h_item, ws, b1, bg1,
                                                   RECU, RECI, nu, ni, nbu);
        edge_main<<<GRID_MAIN, 256, 0, stream>>>(src, dst, RECU, RECI,
                                                 ws + OFF_W2T_E, ws + OFF_W3T_E,
                                                 b2, b3, b4, W4, Wg2, bg2, (float*)d_out, E);
    } else {
        prep_weights_fb<<<(FB_WTOT + 255) / 256, 256, 0, stream>>>(W1, W2, W3, Wg1, ws);
        const int nblk = (E + FB_ETILE - 1) / FB_ETILE;
        fused_edge_kernel_fb<<<nblk, 512, 0, stream>>>(h_user, h_item, src, dst, ws,
                                                       b1, b2, b3, b4, W4, bg1, Wg2, bg2,
                                                       (float*)d_out, E);
    }
}